// Round 1
// baseline (309.433 us; speedup 1.0000x reference)
//
#include <hip/hip_runtime.h>

#define NPTS (512*512)
#define INV_N2 (1.0f/262144.0f)

// ---------------- butterflies ----------------
__device__ __forceinline__ void bfly_dif(float &ar, float &ai, float &br, float &bi,
                                         float wr, float wi) {
  float sr = ar + br, si = ai + bi;
  float dr = ar - br, di = ai - bi;
  ar = sr; ai = si;
  br = dr*wr - di*wi; bi = dr*wi + di*wr;
}
__device__ __forceinline__ void bfly_dit(float &ar, float &ai, float &br, float &bi,
                                         float wr, float wi) {
  float tr = br*wr - bi*wi, ti = br*wi + bi*wr;
  br = ar - tr; bi = ai - ti;
  ar = ar + tr; ai = ai + ti;
}

// 512-pt FFT held in one wave's registers: element n = k*64 + lane (k=reg 0..7).
// Forward: DIF, natural input -> bit-reversed output. Twiddle exp(-i*pi*j/s).
__device__ __forceinline__ void wave_fft512_fwd(float xr[8], float xi[8], int lane) {
  const float PI = 3.14159265358979323846f;
  { // s=256: pairs (k,k+4), j = k*64+lane, rotate by exp(-i*pi/4) per k
    float s0, c0; __sincosf(-PI * (float)lane * (1.0f/256.0f), &s0, &c0);
    float wr = c0, wi = s0;
    const float rr = 0.70710678118654752f, ri = -0.70710678118654752f;
    #pragma unroll
    for (int k = 0; k < 4; ++k) {
      bfly_dif(xr[k], xi[k], xr[k+4], xi[k+4], wr, wi);
      float nr = wr*rr - wi*ri, ni = wr*ri + wi*rr;
      wr = nr; wi = ni;
    }
  }
  { // s=128: pairs (k,k+2), j = (k&1)*64+lane
    float s0, c0; __sincosf(-PI * (float)lane * (1.0f/128.0f), &s0, &c0);
    float w0r = c0, w0i = s0;
    float w1r = s0, w1i = -c0;          // w0 * exp(-i*pi/2)
    bfly_dif(xr[0], xi[0], xr[2], xi[2], w0r, w0i);
    bfly_dif(xr[1], xi[1], xr[3], xi[3], w1r, w1i);
    bfly_dif(xr[4], xi[4], xr[6], xi[6], w0r, w0i);
    bfly_dif(xr[5], xi[5], xr[7], xi[7], w1r, w1i);
  }
  { // s=64: pairs (k,k+1), j = lane
    float s0, c0; __sincosf(-PI * (float)lane * (1.0f/64.0f), &s0, &c0);
    bfly_dif(xr[0], xi[0], xr[1], xi[1], c0, s0);
    bfly_dif(xr[2], xi[2], xr[3], xi[3], c0, s0);
    bfly_dif(xr[4], xi[4], xr[5], xi[5], c0, s0);
    bfly_dif(xr[6], xi[6], xr[7], xi[7], c0, s0);
  }
  // cross-lane stages s=32..1: partner lane = lane ^ s, j = lane & (s-1)
  #pragma unroll
  for (int s = 32; s >= 1; s >>= 1) {
    int j = lane & (s - 1);
    float s0, c0; __sincosf(-PI * (float)j / (float)s, &s0, &c0);
    bool up = (lane & s) != 0;
    #pragma unroll
    for (int k = 0; k < 8; ++k) {
      float rr = __shfl_xor(xr[k], s, 64);
      float ri = __shfl_xor(xi[k], s, 64);
      float sumr = xr[k] + rr, sumi = xi[k] + ri;       // lower keeps a+b
      float dr = rr - xr[k], di = ri - xi[k];           // upper: a-b (recv=a)
      float pr = dr*c0 - di*s0, pq = dr*s0 + di*c0;
      xr[k] = up ? pr : sumr;
      xi[k] = up ? pq : sumi;
    }
  }
}

// Inverse: DIT, bit-reversed input -> natural output (unnormalized). Twiddle exp(+i*pi*j/s).
__device__ __forceinline__ void wave_fft512_inv(float xr[8], float xi[8], int lane) {
  const float PI = 3.14159265358979323846f;
  #pragma unroll
  for (int s = 1; s <= 32; s <<= 1) {
    int j = lane & (s - 1);
    float s0, c0; __sincosf(PI * (float)j / (float)s, &s0, &c0);
    bool up = (lane & s) != 0;
    #pragma unroll
    for (int k = 0; k < 8; ++k) {
      float rr = __shfl_xor(xr[k], s, 64);
      float ri = __shfl_xor(xi[k], s, 64);
      float mr = up ? xr[k] : rr;                       // operand that gets * w
      float mi = up ? xi[k] : ri;
      float tr = mr*c0 - mi*s0, ti = mr*s0 + mi*c0;
      float nr = up ? (rr - tr) : (xr[k] + tr);
      float ni = up ? (ri - ti) : (xi[k] + ti);
      xr[k] = nr; xi[k] = ni;
    }
  }
  { // s=64
    float s0, c0; __sincosf(PI * (float)lane * (1.0f/64.0f), &s0, &c0);
    bfly_dit(xr[0], xi[0], xr[1], xi[1], c0, s0);
    bfly_dit(xr[2], xi[2], xr[3], xi[3], c0, s0);
    bfly_dit(xr[4], xi[4], xr[5], xi[5], c0, s0);
    bfly_dit(xr[6], xi[6], xr[7], xi[7], c0, s0);
  }
  { // s=128
    float s0, c0; __sincosf(PI * (float)lane * (1.0f/128.0f), &s0, &c0);
    float w0r = c0, w0i = s0;
    float w1r = -s0, w1i = c0;          // w0 * exp(+i*pi/2)
    bfly_dit(xr[0], xi[0], xr[2], xi[2], w0r, w0i);
    bfly_dit(xr[1], xi[1], xr[3], xi[3], w1r, w1i);
    bfly_dit(xr[4], xi[4], xr[6], xi[6], w0r, w0i);
    bfly_dit(xr[5], xi[5], xr[7], xi[7], w1r, w1i);
  }
  { // s=256
    float s0, c0; __sincosf(PI * (float)lane * (1.0f/256.0f), &s0, &c0);
    float wr = c0, wi = s0;
    const float rr = 0.70710678118654752f, ri = 0.70710678118654752f;
    #pragma unroll
    for (int k = 0; k < 4; ++k) {
      bfly_dit(xr[k], xi[k], xr[k+4], xi[k+4], wr, wi);
      float nr = wr*rr - wi*ri, ni = wr*ri + wi*rr;
      wr = nr; wi = ni;
    }
  }
}

// ---------------- kernels ----------------
// Build cluster map in bit-reversed, fftshift-folded coordinates, transposed [kv][ku].
// Last-write-wins via atomicMax over (p<<6)|cluster.
__global__ void k_scatter(const int* __restrict__ idxx, const int* __restrict__ idxy,
                          const int* __restrict__ cid, int* __restrict__ cmapT) {
  int p = blockIdx.x * 256 + threadIdx.x;
  if (p >= NPTS) return;
  int u = (idxx[p] + 256) & 511;                 // freq row this mask cell controls
  int v = (idxy[p] + 256) & 511;
  int ku = (int)(__brev((unsigned)u) >> 23);     // storage position after DIF
  int kv = (int)(__brev((unsigned)v) >> 23);
  atomicMax(&cmapT[kv * 512 + ku], (p << 6) | cid[p]);
}

__global__ __launch_bounds__(512) void k_fwd_rows(const float* __restrict__ x,
                                                  float2* __restrict__ Y) {
  int w = threadIdx.x >> 6, lane = threadIdx.x & 63;
  int r = blockIdx.x * 8 + w;                    // global row 0..32767
  const float* row = x + (size_t)r * 512;
  float xr[8], xi[8];
  #pragma unroll
  for (int k = 0; k < 8; ++k) { xr[k] = row[k*64 + lane]; xi[k] = 0.f; }
  wave_fft512_fwd(xr, xi, lane);
  float2* orow = Y + (size_t)r * 512;
  #pragma unroll
  for (int k = 0; k < 8; ++k) orow[k*64 + lane] = make_float2(xr[k], xi[k]);
}

// Column FFT + mask + inverse column FFT, fused. One block = one batch x 8 columns.
__global__ __launch_bounds__(512) void k_cols(float2* __restrict__ Y,
                                              const int* __restrict__ cmapT,
                                              const float* __restrict__ pimp) {
  __shared__ float lre[8 * 520];
  __shared__ float lim[8 * 520];
  __shared__ float pil[64];
  int tid = threadIdx.x;
  int b  = blockIdx.x >> 6;
  int vg = blockIdx.x & 63;
  float2* base = Y + (size_t)b * 512 * 512 + vg * 8;
  #pragma unroll
  for (int rep = 0; rep < 8; ++rep) {            // coalesced tile load
    int e = rep * 512 + tid;
    int i = e >> 3, c = e & 7;
    float2 v = base[(size_t)i * 512 + c];
    lre[c * 520 + i] = v.x; lim[c * 520 + i] = v.y;
  }
  if (tid < 64) pil[tid] = pimp[b * 64 + tid];
  __syncthreads();
  int w = tid >> 6, lane = tid & 63;
  float xr[8], xi[8];
  #pragma unroll
  for (int k = 0; k < 8; ++k) {                  // conflict-free (stride-1) column read
    xr[k] = lre[w * 520 + k*64 + lane];
    xi[k] = lim[w * 520 + k*64 + lane];
  }
  wave_fft512_fwd(xr, xi, lane);
  int kv = vg * 8 + w;
  const int* cm = cmapT + kv * 512;
  #pragma unroll
  for (int k = 0; k < 8; ++k) {                  // mask in bit-reversed storage coords
    int c = cm[k*64 + lane];
    float m = (c < 0 ? 1.0f : pil[c & 63]) * INV_N2;
    xr[k] *= m; xi[k] *= m;
  }
  wave_fft512_inv(xr, xi, lane);
  #pragma unroll
  for (int k = 0; k < 8; ++k) {
    lre[w * 520 + k*64 + lane] = xr[k];
    lim[w * 520 + k*64 + lane] = xi[k];
  }
  __syncthreads();
  #pragma unroll
  for (int rep = 0; rep < 8; ++rep) {            // coalesced tile store
    int e = rep * 512 + tid;
    int i = e >> 3, c = e & 7;
    base[(size_t)i * 512 + c] = make_float2(lre[c * 520 + i], lim[c * 520 + i]);
  }
}

__global__ __launch_bounds__(512) void k_inv_rows(const float2* __restrict__ Y,
                                                  float* __restrict__ out) {
  int w = threadIdx.x >> 6, lane = threadIdx.x & 63;
  int r = blockIdx.x * 8 + w;
  const float2* row = Y + (size_t)r * 512;
  float xr[8], xi[8];
  #pragma unroll
  for (int k = 0; k < 8; ++k) { float2 v = row[k*64 + lane]; xr[k] = v.x; xi[k] = v.y; }
  wave_fft512_inv(xr, xi, lane);
  float* orow = out + (size_t)r * 512;
  #pragma unroll
  for (int k = 0; k < 8; ++k) orow[k*64 + lane] = xr[k];   // real part; 1/N^2 already applied
}

extern "C" void kernel_launch(void* const* d_in, const int* in_sizes, int n_in,
                              void* d_out, int out_size, void* d_ws, size_t ws_size,
                              hipStream_t stream) {
  const float* x    = (const float*)d_in[0];
  const float* pimp = (const float*)d_in[1];
  const int* idxx   = (const int*)d_in[2];
  const int* idxy   = (const int*)d_in[3];
  const int* cid    = (const int*)d_in[4];

  float2* Y   = (float2*)d_ws;                                   // 64*512*512 complex = 128 MB
  int* cmapT  = (int*)((char*)d_ws + (size_t)64*512*512*sizeof(float2)); // 1 MB

  hipMemsetAsync(cmapT, 0xFF, 512 * 512 * sizeof(int), stream);  // all -1 = "mask is 1"
  k_scatter  <<<NPTS / 256, 256, 0, stream>>>(idxx, idxy, cid, cmapT);
  k_fwd_rows <<<4096, 512, 0, stream>>>(x, Y);
  k_cols     <<<4096, 512, 0, stream>>>(Y, cmapT, pimp);
  k_inv_rows <<<4096, 512, 0, stream>>>(Y, (float*)d_out);
}

// Round 2
// 286.664 us; speedup vs baseline: 1.0794x; 1.0794x over previous
//
#include <hip/hip_runtime.h>

#define NPTS (512*512)
#define INV_N2 (1.0f/262144.0f)

typedef unsigned u32x2 __attribute__((ext_vector_type(2)));

// Raw HW transcendentals: v_sin_f32/v_cos_f32 take input in REVOLUTIONS.
// All our angles are exact binary fractions of a revolution -> exact args.
__device__ __forceinline__ float hsin(float rev) { return __builtin_amdgcn_sinf(rev); }
__device__ __forceinline__ float hcos(float rev) { return __builtin_amdgcn_cosf(rev); }

// ---------------- cross-lane exchange primitives (partner value at lane^S) ----
template<int CTRL>
__device__ __forceinline__ float xdpp(float x) {
  int v = __float_as_int(x);
  return __int_as_float(__builtin_amdgcn_update_dpp(v, v, CTRL, 0xF, 0xF, true));
}
__device__ __forceinline__ float xs1(float x) { return xdpp<0xB1>(x); }   // quad_perm [1,0,3,2]
__device__ __forceinline__ float xs2(float x) { return xdpp<0x4E>(x); }   // quad_perm [2,3,0,1]
__device__ __forceinline__ float xs8(float x) { return xdpp<0x128>(x); }  // row_ror:8 == xor8 in 16
__device__ __forceinline__ float xs4(float x) {                           // ds_swizzle xor4
  return __int_as_float(__builtin_amdgcn_ds_swizzle(__float_as_int(x), 0x101F));
}
__device__ __forceinline__ float xs16(float x) {
#if __has_builtin(__builtin_amdgcn_permlane16_swap)
  u32x2 r = __builtin_amdgcn_permlane16_swap(__float_as_uint(x), __float_as_uint(x), false, false);
  // r[0] = rows {0,0,2,2}, r[1] = rows {1,1,3,3}
  return __uint_as_float((threadIdx.x & 16) ? r[0] : r[1]);
#else
  return __int_as_float(__builtin_amdgcn_ds_swizzle(__float_as_int(x), 0x401F));
#endif
}
__device__ __forceinline__ float xs32(float x) {
#if __has_builtin(__builtin_amdgcn_permlane32_swap)
  u32x2 r = __builtin_amdgcn_permlane32_swap(__float_as_uint(x), __float_as_uint(x), false, false);
  // r[0] = {lo,lo}, r[1] = {hi,hi}
  return __uint_as_float((threadIdx.x & 32) ? r[0] : r[1]);
#else
  return __shfl_xor(x, 32, 64);
#endif
}

// ---------------- register-local butterflies ----------------
__device__ __forceinline__ void bfly_dif(float &ar, float &ai, float &br, float &bi,
                                         float wr, float wi) {
  float sr = ar + br, si = ai + bi;
  float dr = ar - br, di = ai - bi;
  ar = sr; ai = si;
  br = dr*wr - di*wi; bi = dr*wi + di*wr;
}
__device__ __forceinline__ void bfly_dit(float &ar, float &ai, float &br, float &bi,
                                         float wr, float wi) {
  float tr = br*wr - bi*wi, ti = br*wi + bi*wr;
  br = ar - tr; bi = ai - ti;
  ar = ar + tr; ai = ai + ti;
}

// Cross-lane stage, forward DIF: out = (r + sg*x) * W, W=(1,0) lower / w upper.
#define FWD_XSTAGE(S, XCHG) { \
  const float rev = -(float)(lane & (S-1)) * (0.5f/(float)(S)); \
  float s0 = hsin(rev), c0 = hcos(rev); \
  const bool up = (lane & (S)) != 0; \
  const float sg = up ? -1.0f : 1.0f; \
  const float wr = up ? c0 : 1.0f; \
  const float wi = up ? s0 : 0.0f; \
  _Pragma("unroll") for (int k = 0; k < 8; ++k) { \
    float rr = XCHG(xr[k]); float ri = XCHG(xi[k]); \
    float vr = fmaf(sg, xr[k], rr); float vi = fmaf(sg, xi[k], ri); \
    xr[k] = vr*wr - vi*wi; xi[k] = vr*wi + vi*wr; } }

// Cross-lane stage, inverse DIT: out = n + W*m, m=(up?x:r), n=(up?r:x), W=(up?-w:w).
#define INV_XSTAGE(S, XCHG) { \
  const float rev = (float)(lane & (S-1)) * (0.5f/(float)(S)); \
  float s0 = hsin(rev), c0 = hcos(rev); \
  const bool up = (lane & (S)) != 0; \
  const float wr = up ? -c0 : c0; \
  const float wi = up ? -s0 : s0; \
  _Pragma("unroll") for (int k = 0; k < 8; ++k) { \
    float rr = XCHG(xr[k]); float ri = XCHG(xi[k]); \
    float mr = up ? xr[k] : rr; float mi = up ? xi[k] : ri; \
    float nr = up ? rr : xr[k]; float ni = up ? ri : xi[k]; \
    xr[k] = nr + (mr*wr - mi*wi); xi[k] = ni + (mr*wi + mi*wr); } }

// 512-pt FFT in one wave's registers: element n = k*64 + lane.
// Forward DIF: natural in -> bit-reversed out.
__device__ __forceinline__ void wave_fft512_fwd(float xr[8], float xi[8], int lane) {
  { // s=256: twiddle exp(-i*pi*(k*64+lane)/256); per-k rotation exp(-i*pi/4)
    float rev = -(float)lane * (1.0f/512.0f);
    float s0 = hsin(rev), c0 = hcos(rev);
    float wr = c0, wi = s0;
    const float rr8 = 0.70710678118654752f, ri8 = -0.70710678118654752f;
    #pragma unroll
    for (int k = 0; k < 4; ++k) {
      bfly_dif(xr[k], xi[k], xr[k+4], xi[k+4], wr, wi);
      float nr = wr*rr8 - wi*ri8, ni = wr*ri8 + wi*rr8;
      wr = nr; wi = ni;
    }
  }
  { // s=128
    float rev = -(float)lane * (1.0f/256.0f);
    float s0 = hsin(rev), c0 = hcos(rev);
    float w0r = c0, w0i = s0;
    float w1r = s0, w1i = -c0;          // w0 * exp(-i*pi/2)
    bfly_dif(xr[0], xi[0], xr[2], xi[2], w0r, w0i);
    bfly_dif(xr[1], xi[1], xr[3], xi[3], w1r, w1i);
    bfly_dif(xr[4], xi[4], xr[6], xi[6], w0r, w0i);
    bfly_dif(xr[5], xi[5], xr[7], xi[7], w1r, w1i);
  }
  { // s=64
    float rev = -(float)lane * (1.0f/128.0f);
    float s0 = hsin(rev), c0 = hcos(rev);
    bfly_dif(xr[0], xi[0], xr[1], xi[1], c0, s0);
    bfly_dif(xr[2], xi[2], xr[3], xi[3], c0, s0);
    bfly_dif(xr[4], xi[4], xr[5], xi[5], c0, s0);
    bfly_dif(xr[6], xi[6], xr[7], xi[7], c0, s0);
  }
  FWD_XSTAGE(32, xs32)
  FWD_XSTAGE(16, xs16)
  FWD_XSTAGE(8,  xs8)
  FWD_XSTAGE(4,  xs4)
  FWD_XSTAGE(2,  xs2)
  { // s=1: W == (1,0) both halves -> just sum/diff
    const bool up = (lane & 1) != 0;
    const float sg = up ? -1.0f : 1.0f;
    #pragma unroll
    for (int k = 0; k < 8; ++k) {
      float rr = xs1(xr[k]); float ri = xs1(xi[k]);
      xr[k] = fmaf(sg, xr[k], rr); xi[k] = fmaf(sg, xi[k], ri);
    }
  }
}

// Inverse DIT: bit-reversed in -> natural out (unnormalized).
__device__ __forceinline__ void wave_fft512_inv(float xr[8], float xi[8], int lane) {
  { // s=1
    const bool up = (lane & 1) != 0;
    const float sg = up ? -1.0f : 1.0f;
    #pragma unroll
    for (int k = 0; k < 8; ++k) {
      float rr = xs1(xr[k]); float ri = xs1(xi[k]);
      xr[k] = fmaf(sg, xr[k], rr); xi[k] = fmaf(sg, xi[k], ri);
    }
  }
  INV_XSTAGE(2,  xs2)
  INV_XSTAGE(4,  xs4)
  INV_XSTAGE(8,  xs8)
  INV_XSTAGE(16, xs16)
  INV_XSTAGE(32, xs32)
  { // s=64
    float rev = (float)lane * (1.0f/128.0f);
    float s0 = hsin(rev), c0 = hcos(rev);
    bfly_dit(xr[0], xi[0], xr[1], xi[1], c0, s0);
    bfly_dit(xr[2], xi[2], xr[3], xi[3], c0, s0);
    bfly_dit(xr[4], xi[4], xr[5], xi[5], c0, s0);
    bfly_dit(xr[6], xi[6], xr[7], xi[7], c0, s0);
  }
  { // s=128
    float rev = (float)lane * (1.0f/256.0f);
    float s0 = hsin(rev), c0 = hcos(rev);
    float w0r = c0, w0i = s0;
    float w1r = -s0, w1i = c0;          // w0 * exp(+i*pi/2)
    bfly_dit(xr[0], xi[0], xr[2], xi[2], w0r, w0i);
    bfly_dit(xr[1], xi[1], xr[3], xi[3], w1r, w1i);
    bfly_dit(xr[4], xi[4], xr[6], xi[6], w0r, w0i);
    bfly_dit(xr[5], xi[5], xr[7], xi[7], w1r, w1i);
  }
  { // s=256
    float rev = (float)lane * (1.0f/512.0f);
    float s0 = hsin(rev), c0 = hcos(rev);
    float wr = c0, wi = s0;
    const float rr8 = 0.70710678118654752f, ri8 = 0.70710678118654752f;
    #pragma unroll
    for (int k = 0; k < 4; ++k) {
      bfly_dit(xr[k], xi[k], xr[k+4], xi[k+4], wr, wi);
      float nr = wr*rr8 - wi*ri8, ni = wr*ri8 + wi*rr8;
      wr = nr; wi = ni;
    }
  }
}

// ---------------- kernels ----------------
__global__ void k_scatter(const int* __restrict__ idxx, const int* __restrict__ idxy,
                          const int* __restrict__ cid, int* __restrict__ cmapT) {
  int p = blockIdx.x * 256 + threadIdx.x;
  if (p >= NPTS) return;
  int u = (idxx[p] + 256) & 511;
  int v = (idxy[p] + 256) & 511;
  int ku = (int)(__brev((unsigned)u) >> 23);
  int kv = (int)(__brev((unsigned)v) >> 23);
  atomicMax(&cmapT[kv * 512 + ku], (p << 6) | cid[p]);
}

__global__ __launch_bounds__(512) void k_fwd_rows(const float* __restrict__ x,
                                                  float2* __restrict__ Y) {
  int w = threadIdx.x >> 6, lane = threadIdx.x & 63;
  int r = blockIdx.x * 8 + w;
  const float* row = x + (size_t)r * 512;
  float xr[8], xi[8];
  #pragma unroll
  for (int k = 0; k < 8; ++k) { xr[k] = row[k*64 + lane]; xi[k] = 0.f; }
  wave_fft512_fwd(xr, xi, lane);
  float2* orow = Y + (size_t)r * 512;
  #pragma unroll
  for (int k = 0; k < 8; ++k) orow[k*64 + lane] = make_float2(xr[k], xi[k]);
}

// Column FFT + mask + inverse column FFT, fused. One block = one batch x 8 columns.
__global__ __launch_bounds__(512) void k_cols(float2* __restrict__ Y,
                                              const int* __restrict__ cmapT,
                                              const float* __restrict__ pimp) {
  __shared__ float2 tile[8 * 520];
  __shared__ float pil[64];
  int tid = threadIdx.x;
  int b  = blockIdx.x >> 6;
  int vg = blockIdx.x & 63;
  float2* base = Y + (size_t)b * 512 * 512 + vg * 8;
  #pragma unroll
  for (int rep = 0; rep < 4; ++rep) {            // coalesced float4 tile load
    int m = rep * 512 + tid;                     // 0..2047 float4s
    int i = m >> 2, cp = m & 3;
    float4 v = ((const float4*)base)[(size_t)i * 256 + cp];
    tile[(2*cp)   * 520 + i] = make_float2(v.x, v.y);
    tile[(2*cp+1) * 520 + i] = make_float2(v.z, v.w);
  }
  if (tid < 64) pil[tid] = pimp[b * 64 + tid];
  __syncthreads();
  int w = tid >> 6, lane = tid & 63;
  float xr[8], xi[8];
  #pragma unroll
  for (int k = 0; k < 8; ++k) {                  // b64 column read (conflict-free)
    float2 t = tile[w * 520 + k*64 + lane];
    xr[k] = t.x; xi[k] = t.y;
  }
  wave_fft512_fwd(xr, xi, lane);
  int kv = vg * 8 + w;
  const int* cm = cmapT + kv * 512;
  #pragma unroll
  for (int k = 0; k < 8; ++k) {                  // mask in bit-reversed storage coords
    int c = cm[k*64 + lane];
    float m = (c < 0 ? 1.0f : pil[c & 63]) * INV_N2;
    xr[k] *= m; xi[k] *= m;
  }
  wave_fft512_inv(xr, xi, lane);
  #pragma unroll
  for (int k = 0; k < 8; ++k)
    tile[w * 520 + k*64 + lane] = make_float2(xr[k], xi[k]);
  __syncthreads();
  #pragma unroll
  for (int rep = 0; rep < 4; ++rep) {            // coalesced float4 tile store
    int m = rep * 512 + tid;
    int i = m >> 2, cp = m & 3;
    float2 a = tile[(2*cp)   * 520 + i];
    float2 c = tile[(2*cp+1) * 520 + i];
    ((float4*)base)[(size_t)i * 256 + cp] = make_float4(a.x, a.y, c.x, c.y);
  }
}

__global__ __launch_bounds__(512) void k_inv_rows(const float2* __restrict__ Y,
                                                  float* __restrict__ out) {
  int w = threadIdx.x >> 6, lane = threadIdx.x & 63;
  int r = blockIdx.x * 8 + w;
  const float2* row = Y + (size_t)r * 512;
  float xr[8], xi[8];
  #pragma unroll
  for (int k = 0; k < 8; ++k) { float2 v = row[k*64 + lane]; xr[k] = v.x; xi[k] = v.y; }
  wave_fft512_inv(xr, xi, lane);
  float* orow = out + (size_t)r * 512;
  #pragma unroll
  for (int k = 0; k < 8; ++k) orow[k*64 + lane] = xr[k];   // 1/N^2 folded into mask
}

extern "C" void kernel_launch(void* const* d_in, const int* in_sizes, int n_in,
                              void* d_out, int out_size, void* d_ws, size_t ws_size,
                              hipStream_t stream) {
  const float* x    = (const float*)d_in[0];
  const float* pimp = (const float*)d_in[1];
  const int* idxx   = (const int*)d_in[2];
  const int* idxy   = (const int*)d_in[3];
  const int* cid    = (const int*)d_in[4];

  float2* Y   = (float2*)d_ws;                                          // 128 MB
  int* cmapT  = (int*)((char*)d_ws + (size_t)64*512*512*sizeof(float2)); // 1 MB

  hipMemsetAsync(cmapT, 0xFF, 512 * 512 * sizeof(int), stream);
  k_scatter  <<<NPTS / 256, 256, 0, stream>>>(idxx, idxy, cid, cmapT);
  k_fwd_rows <<<4096, 512, 0, stream>>>(x, Y);
  k_cols     <<<4096, 512, 0, stream>>>(Y, cmapT, pimp);
  k_inv_rows <<<4096, 512, 0, stream>>>(Y, (float*)d_out);
}

// Round 3
// 229.240 us; speedup vs baseline: 1.3498x; 1.2505x over previous
//
#include <hip/hip_runtime.h>

#define INV_N2 (1.0f/262144.0f)
#define RS 264      // Yh row stride in float2 (257 used + pad, 16B-aligned rows)
#define TS 520      // k_cols LDS tile plane stride in floats (512 + 8)
#define YH_F2 ((size_t)32768 * RS)

typedef unsigned u32x2 __attribute__((ext_vector_type(2)));

__device__ __forceinline__ int brev9(int v) { return (int)(__brev((unsigned)v) >> 23); }

// v_sin_f32/v_cos_f32: input in revolutions; our angles are exact binary fractions.
__device__ __forceinline__ float hsin(float rev) { return __builtin_amdgcn_sinf(rev); }
__device__ __forceinline__ float hcos(float rev) { return __builtin_amdgcn_cosf(rev); }

// ---------------- cross-lane exchange (value at lane^S) ----------------
template<int CTRL>
__device__ __forceinline__ float xdpp(float x) {
  int v = __float_as_int(x);
  return __int_as_float(__builtin_amdgcn_update_dpp(v, v, CTRL, 0xF, 0xF, true));
}
__device__ __forceinline__ float xs1(float x) { return xdpp<0xB1>(x); }   // quad_perm [1,0,3,2]
__device__ __forceinline__ float xs2(float x) { return xdpp<0x4E>(x); }   // quad_perm [2,3,0,1]
__device__ __forceinline__ float xs8(float x) { return xdpp<0x128>(x); }  // row_ror:8
__device__ __forceinline__ float xs4(float x) {                           // ds_swizzle xor4
  return __int_as_float(__builtin_amdgcn_ds_swizzle(__float_as_int(x), 0x101F));
}
__device__ __forceinline__ float xs16(float x) {
#if __has_builtin(__builtin_amdgcn_permlane16_swap)
  u32x2 r = __builtin_amdgcn_permlane16_swap(__float_as_uint(x), __float_as_uint(x), false, false);
  return __uint_as_float((threadIdx.x & 16) ? r[0] : r[1]);
#else
  return __int_as_float(__builtin_amdgcn_ds_swizzle(__float_as_int(x), 0x401F));
#endif
}
__device__ __forceinline__ float xs32(float x) {
#if __has_builtin(__builtin_amdgcn_permlane32_swap)
  u32x2 r = __builtin_amdgcn_permlane32_swap(__float_as_uint(x), __float_as_uint(x), false, false);
  return __uint_as_float((threadIdx.x & 32) ? r[0] : r[1]);
#else
  return __shfl_xor(x, 32, 64);
#endif
}

// ---------------- register-local butterflies ----------------
__device__ __forceinline__ void bfly_dif(float &ar, float &ai, float &br, float &bi,
                                         float wr, float wi) {
  float sr = ar + br, si = ai + bi;
  float dr = ar - br, di = ai - bi;
  ar = sr; ai = si;
  br = dr*wr - di*wi; bi = dr*wi + di*wr;
}
__device__ __forceinline__ void bfly_dit(float &ar, float &ai, float &br, float &bi,
                                         float wr, float wi) {
  float tr = br*wr - bi*wi, ti = br*wi + bi*wr;
  br = ar - tr; bi = ai - ti;
  ar = ar + tr; ai = ai + ti;
}

// Forward DIF cross-lane stage: exchange, combine (sg), then per-lane twiddle (1 for low half).
#define FWD_XSTAGE(S, XCHG) { \
  const float rev = -(float)(lane & (S-1)) * (0.5f/(float)(S)); \
  float s0 = hsin(rev), c0 = hcos(rev); \
  const bool up = (lane & (S)) != 0; \
  const float sg = up ? -1.0f : 1.0f; \
  const float wr = up ? c0 : 1.0f; \
  const float wi = up ? s0 : 0.0f; \
  _Pragma("unroll") for (int k = 0; k < 8; ++k) { \
    float rr = XCHG(xr[k]); float ri = XCHG(xi[k]); \
    float vr = fmaf(sg, xr[k], rr); float vi = fmaf(sg, xi[k], ri); \
    xr[k] = vr*wr - vi*wi; xi[k] = vr*wi + vi*wr; } }

// Inverse DIT cross-lane stage, select-free: twiddle own value (1 for low half),
// exchange products, out = recv + sg*own.  low: x+w*r  up: r_recv - w*x. 6 VALU + 2 DPP.
#define INV_XSTAGE(S, XCHG) { \
  const float rev = (float)(lane & (S-1)) * (0.5f/(float)(S)); \
  float s0 = hsin(rev), c0 = hcos(rev); \
  const bool up = (lane & (S)) != 0; \
  const float wr = up ? c0 : 1.0f; \
  const float wi = up ? s0 : 0.0f; \
  const float sg = up ? -1.0f : 1.0f; \
  _Pragma("unroll") for (int k = 0; k < 8; ++k) { \
    float zr = xr[k]*wr - xi[k]*wi; \
    float zi = xr[k]*wi + xi[k]*wr; \
    float rr = XCHG(zr); float ri = XCHG(zi); \
    xr[k] = fmaf(sg, zr, rr); xi[k] = fmaf(sg, zi, ri); } }

// 512-pt FFT in one wave's registers: element n = k*64 + lane.
// Forward DIF: natural in -> bit-reversed out (position n holds X[brev9(n)]).
__device__ __forceinline__ void wave_fft512_fwd(float xr[8], float xi[8], int lane) {
  { // s=256
    float rev = -(float)lane * (1.0f/512.0f);
    float s0 = hsin(rev), c0 = hcos(rev);
    float wr = c0, wi = s0;
    const float rr8 = 0.70710678118654752f, ri8 = -0.70710678118654752f;
    #pragma unroll
    for (int k = 0; k < 4; ++k) {
      bfly_dif(xr[k], xi[k], xr[k+4], xi[k+4], wr, wi);
      float nr = wr*rr8 - wi*ri8, ni = wr*ri8 + wi*rr8;
      wr = nr; wi = ni;
    }
  }
  { // s=128
    float rev = -(float)lane * (1.0f/256.0f);
    float s0 = hsin(rev), c0 = hcos(rev);
    float w0r = c0, w0i = s0;
    float w1r = s0, w1i = -c0;          // w0 * exp(-i*pi/2)
    bfly_dif(xr[0], xi[0], xr[2], xi[2], w0r, w0i);
    bfly_dif(xr[1], xi[1], xr[3], xi[3], w1r, w1i);
    bfly_dif(xr[4], xi[4], xr[6], xi[6], w0r, w0i);
    bfly_dif(xr[5], xi[5], xr[7], xi[7], w1r, w1i);
  }
  { // s=64
    float rev = -(float)lane * (1.0f/128.0f);
    float s0 = hsin(rev), c0 = hcos(rev);
    bfly_dif(xr[0], xi[0], xr[1], xi[1], c0, s0);
    bfly_dif(xr[2], xi[2], xr[3], xi[3], c0, s0);
    bfly_dif(xr[4], xi[4], xr[5], xi[5], c0, s0);
    bfly_dif(xr[6], xi[6], xr[7], xi[7], c0, s0);
  }
  FWD_XSTAGE(32, xs32)
  FWD_XSTAGE(16, xs16)
  FWD_XSTAGE(8,  xs8)
  FWD_XSTAGE(4,  xs4)
  FWD_XSTAGE(2,  xs2)
  { // s=1: twiddle is 1 both halves
    const float sg = (lane & 1) ? -1.0f : 1.0f;
    #pragma unroll
    for (int k = 0; k < 8; ++k) {
      float rr = xs1(xr[k]); float ri = xs1(xi[k]);
      xr[k] = fmaf(sg, xr[k], rr); xi[k] = fmaf(sg, xi[k], ri);
    }
  }
}

// Inverse DIT: bit-reversed in -> natural out (unnormalized).
__device__ __forceinline__ void wave_fft512_inv(float xr[8], float xi[8], int lane) {
  { // s=1
    const float sg = (lane & 1) ? -1.0f : 1.0f;
    #pragma unroll
    for (int k = 0; k < 8; ++k) {
      float rr = xs1(xr[k]); float ri = xs1(xi[k]);
      xr[k] = fmaf(sg, xr[k], rr); xi[k] = fmaf(sg, xi[k], ri);
    }
  }
  INV_XSTAGE(2,  xs2)
  INV_XSTAGE(4,  xs4)
  INV_XSTAGE(8,  xs8)
  INV_XSTAGE(16, xs16)
  INV_XSTAGE(32, xs32)
  { // s=64
    float rev = (float)lane * (1.0f/128.0f);
    float s0 = hsin(rev), c0 = hcos(rev);
    bfly_dit(xr[0], xi[0], xr[1], xi[1], c0, s0);
    bfly_dit(xr[2], xi[2], xr[3], xi[3], c0, s0);
    bfly_dit(xr[4], xi[4], xr[5], xi[5], c0, s0);
    bfly_dit(xr[6], xi[6], xr[7], xi[7], c0, s0);
  }
  { // s=128
    float rev = (float)lane * (1.0f/256.0f);
    float s0 = hsin(rev), c0 = hcos(rev);
    float w0r = c0, w0i = s0;
    float w1r = -s0, w1i = c0;          // w0 * exp(+i*pi/2)
    bfly_dit(xr[0], xi[0], xr[2], xi[2], w0r, w0i);
    bfly_dit(xr[1], xi[1], xr[3], xi[3], w1r, w1i);
    bfly_dit(xr[4], xi[4], xr[6], xi[6], w0r, w0i);
    bfly_dit(xr[5], xi[5], xr[7], xi[7], w1r, w1i);
  }
  { // s=256
    float rev = (float)lane * (1.0f/512.0f);
    float s0 = hsin(rev), c0 = hcos(rev);
    float wr = c0, wi = s0;
    const float rr8 = 0.70710678118654752f, ri8 = 0.70710678118654752f;
    #pragma unroll
    for (int k = 0; k < 4; ++k) {
      bfly_dit(xr[k], xi[k], xr[k+4], xi[k+4], wr, wi);
      float nr = wr*rr8 - wi*ri8, ni = wr*ri8 + wi*rr8;
      wr = nr; wi = ni;
    }
  }
}

// ---------------- kernels ----------------
// Natural-coords winner map W[u*512+v], last-write-wins via atomicMax on (p<<6)|cid.
__global__ void k_scatter(const int* __restrict__ idxx, const int* __restrict__ idxy,
                          const int* __restrict__ cid, int* __restrict__ W) {
  int p = blockIdx.x * 256 + threadIdx.x;
  int u = (idxx[p] + 256) & 511;
  int v = (idxy[p] + 256) & 511;
  atomicMax(&W[u * 512 + v], (p << 6) | cid[p]);
}

// pk[j*512+n]: packed (cid_mirror<<7)|cid for stored column j at storage row n.
// Symmetrized mask coords: (u,v) and (-u,-v). 127 = "no point" (mask 1).
__global__ void k_pack(const int* __restrict__ W, int* __restrict__ pk) {
  int idx = blockIdx.x * 256 + threadIdx.x;
  if (idx >= 264 * 512) return;
  int j = idx >> 9, n = idx & 511;
  int out = (127 << 7) | 127;
  if (j < 257) {
    int v = (j == 256) ? 256 : brev9(2 * j);
    int u = brev9(n);
    int c1 = W[u * 512 + v];
    int c2 = W[((512 - u) & 511) * 512 + ((512 - v) & 511)];
    int a = (c1 < 0) ? 127 : (c1 & 63);
    int b = (c2 < 0) ? 127 : (c2 & 63);
    out = (b << 7) | a;
  }
  pk[j * 512 + n] = out;
}

// Row FFT; store half-spectrum: even storage n -> j=n/2, n=1 -> j=256.
__global__ __launch_bounds__(512) void k_fwd_rows(const float* __restrict__ x,
                                                  float2* __restrict__ Yh) {
  int w = threadIdx.x >> 6, lane = threadIdx.x & 63;
  int r = blockIdx.x * 8 + w;
  const float* row = x + (size_t)r * 512;
  float xr[8], xi[8];
  #pragma unroll
  for (int k = 0; k < 8; ++k) { xr[k] = row[k*64 + lane]; xi[k] = 0.f; }
  wave_fft512_fwd(xr, xi, lane);
  float2* orow = Yh + (size_t)r * RS;
  if (!(lane & 1)) {
    #pragma unroll
    for (int k = 0; k < 8; ++k) orow[k*32 + (lane >> 1)] = make_float2(xr[k], xi[k]);
  } else if (lane == 1) {
    orow[256] = make_float2(xr[0], xi[0]);
  }
}

// Column FFT + symmetrized mask + inverse column FFT over 264 stored columns
// (257 real + 7 padding; padding stores land in the pad region, never read).
__global__ __launch_bounds__(512) void k_cols(float2* __restrict__ Yh,
                                              const int* __restrict__ pk,
                                              const float* __restrict__ pimp) {
  __shared__ float lre[8 * TS], lim[8 * TS];
  __shared__ float pilx[128];
  int tid = threadIdx.x;
  int b = blockIdx.x / 33, g = blockIdx.x % 33;
  float2* base = Yh + (size_t)b * 512 * RS + g * 8;
  #pragma unroll
  for (int rep = 0; rep < 4; ++rep) {            // coalesced float4 tile load
    int m = rep * 512 + tid;
    int i = m >> 2, cp = m & 3;
    float4 v = *(const float4*)(base + (size_t)i * RS + 2 * cp);
    lre[(2*cp)  *TS + i] = v.x; lim[(2*cp)  *TS + i] = v.y;
    lre[(2*cp+1)*TS + i] = v.z; lim[(2*cp+1)*TS + i] = v.w;
  }
  if (tid < 128) pilx[tid] = (tid < 64) ? pimp[b * 64 + tid] : 1.0f;
  __syncthreads();
  int w = tid >> 6, lane = tid & 63;
  float xr[8], xi[8];
  #pragma unroll
  for (int k = 0; k < 8; ++k) {                  // 2-way (free) b32 column reads
    xr[k] = lre[w*TS + k*64 + lane];
    xi[k] = lim[w*TS + k*64 + lane];
  }
  wave_fft512_fwd(xr, xi, lane);
  const int* cm = pk + (g * 8 + w) * 512;
  #pragma unroll
  for (int k = 0; k < 8; ++k) {                  // branchless symmetrized mask
    int p = cm[k*64 + lane];
    float mm = 0.5f * (pilx[p & 127] + pilx[(p >> 7) & 127]) * INV_N2;
    xr[k] *= mm; xi[k] *= mm;
  }
  wave_fft512_inv(xr, xi, lane);
  #pragma unroll
  for (int k = 0; k < 8; ++k) {
    lre[w*TS + k*64 + lane] = xr[k];
    lim[w*TS + k*64 + lane] = xi[k];
  }
  __syncthreads();
  #pragma unroll
  for (int rep = 0; rep < 4; ++rep) {            // coalesced float4 tile store
    int m = rep * 512 + tid;
    int i = m >> 2, cp = m & 3;
    *(float4*)(base + (size_t)i * RS + 2 * cp) =
      make_float4(lre[(2*cp)*TS + i], lim[(2*cp)*TS + i],
                  lre[(2*cp+1)*TS + i], lim[(2*cp+1)*TS + i]);
  }
}

// Hermitian mirror + inverse row FFT -> real output.
__global__ __launch_bounds__(512) void k_inv_rows(const float2* __restrict__ Yh,
                                                  float* __restrict__ out) {
  __shared__ float lre[8 * RS], lim[8 * RS];
  int tid = threadIdx.x;
  int w = tid >> 6, lane = tid & 63;
  int r = blockIdx.x * 8 + w;
  const float2* rowp = Yh + (size_t)r * RS;
  #pragma unroll
  for (int k2 = 0; k2 < 5; ++k2) {               // stage half-row (257 float2) in LDS
    int idx = k2 * 64 + lane;
    if (idx < 257) {
      float2 v = rowp[idx];
      lre[w*RS + idx] = v.x; lim[w*RS + idx] = v.y;
    }
  }
  float xr[8], xi[8];
  #pragma unroll
  for (int k = 0; k < 8; ++k) {                  // mirror: even n direct, odd n conj from -v
    int n = k * 64 + lane;
    int v9 = brev9(n);
    int j2 = brev9(512 - v9) >> 1;               // valid when n odd, n!=1
    int j = (n & 1) ? ((n == 1) ? 256 : j2) : (n >> 1);
    float sgn = ((n & 1) && (n != 1)) ? -1.f : 1.f;
    xr[k] = lre[w*RS + j];
    xi[k] = sgn * lim[w*RS + j];
  }
  wave_fft512_inv(xr, xi, lane);
  float* orow = out + (size_t)r * 512;
  #pragma unroll
  for (int k = 0; k < 8; ++k) orow[k*64 + lane] = xr[k];
}

extern "C" void kernel_launch(void* const* d_in, const int* in_sizes, int n_in,
                              void* d_out, int out_size, void* d_ws, size_t ws_size,
                              hipStream_t stream) {
  const float* x    = (const float*)d_in[0];
  const float* pimp = (const float*)d_in[1];
  const int* idxx   = (const int*)d_in[2];
  const int* idxy   = (const int*)d_in[3];
  const int* cid    = (const int*)d_in[4];

  float2* Yh = (float2*)d_ws;                                    // 32768*264*8 = 66 MB
  int* W  = (int*)((char*)d_ws + YH_F2 * sizeof(float2));        // 1 MB
  int* pk = W + 512 * 512;                                       // 0.53 MB

  hipMemsetAsync(W, 0xFF, 512 * 512 * sizeof(int), stream);      // -1 = empty
  k_scatter  <<<1024, 256, 0, stream>>>(idxx, idxy, cid, W);
  k_pack     <<<(264 * 512 + 255) / 256, 256, 0, stream>>>(W, pk);
  k_fwd_rows <<<4096, 512, 0, stream>>>(x, Yh);
  k_cols     <<<64 * 33, 512, 0, stream>>>(Yh, pk, pimp);
  k_inv_rows <<<4096, 512, 0, stream>>>(Yh, (float*)d_out);
}

// Round 4
// 213.974 us; speedup vs baseline: 1.4461x; 1.0713x over previous
//
#include <hip/hip_runtime.h>

#define INV_N2 (1.0f/262144.0f)
#define RS 264      // Yh row stride in float2 (257 used + pad)
#define TS 520      // k_cols LDS plane stride in floats
#define YH_F2 ((size_t)32768 * RS)

typedef unsigned u32x2 __attribute__((ext_vector_type(2)));

__device__ __forceinline__ int brev9(int v) { return (int)(__brev((unsigned)v) >> 23); }
__device__ __forceinline__ float hsin(float rev) { return __builtin_amdgcn_sinf(rev); }
__device__ __forceinline__ float hcos(float rev) { return __builtin_amdgcn_cosf(rev); }

// ---------------- cross-lane exchange (value at lane^S) ----------------
template<int CTRL>
__device__ __forceinline__ float xdpp(float x) {
  int v = __float_as_int(x);
  return __int_as_float(__builtin_amdgcn_update_dpp(v, v, CTRL, 0xF, 0xF, true));
}
__device__ __forceinline__ float xs1(float x) { return xdpp<0xB1>(x); }
__device__ __forceinline__ float xs2(float x) { return xdpp<0x4E>(x); }
__device__ __forceinline__ float xs8(float x) { return xdpp<0x128>(x); }
__device__ __forceinline__ float xs4(float x) {
  return __int_as_float(__builtin_amdgcn_ds_swizzle(__float_as_int(x), 0x101F));
}
__device__ __forceinline__ float xs16(float x) {
#if __has_builtin(__builtin_amdgcn_permlane16_swap)
  u32x2 r = __builtin_amdgcn_permlane16_swap(__float_as_uint(x), __float_as_uint(x), false, false);
  return __uint_as_float((threadIdx.x & 16) ? r[0] : r[1]);
#else
  return __int_as_float(__builtin_amdgcn_ds_swizzle(__float_as_int(x), 0x401F));
#endif
}
__device__ __forceinline__ float xs32(float x) {
#if __has_builtin(__builtin_amdgcn_permlane32_swap)
  u32x2 r = __builtin_amdgcn_permlane32_swap(__float_as_uint(x), __float_as_uint(x), false, false);
  return __uint_as_float((threadIdx.x & 32) ? r[0] : r[1]);
#else
  return __shfl_xor(x, 32, 64);
#endif
}

// ---------------- per-lane stage twiddles (positive angles, in revolutions) ----
// idx: 0:lane/512  1:lane/256  2:lane/128  3:(lane&31)/64  4:(lane&15)/32
//      5:(lane&7)/16  6:(lane&3)/8  7:(lane&1)/4
struct Tw { float c[8], s[8]; };
__device__ __forceinline__ Tw make_tw(int lane) {
  Tw t;
  float a0 = (float)lane        * (1.0f/512.0f);
  float a1 = (float)lane        * (1.0f/256.0f);
  float a2 = (float)lane        * (1.0f/128.0f);
  float a3 = (float)(lane & 31) * (1.0f/64.0f);
  float a4 = (float)(lane & 15) * (1.0f/32.0f);
  float a5 = (float)(lane & 7)  * (1.0f/16.0f);
  float a6 = (float)(lane & 3)  * (1.0f/8.0f);
  float a7 = (float)(lane & 1)  * (1.0f/4.0f);
  t.c[0]=hcos(a0); t.s[0]=hsin(a0); t.c[1]=hcos(a1); t.s[1]=hsin(a1);
  t.c[2]=hcos(a2); t.s[2]=hsin(a2); t.c[3]=hcos(a3); t.s[3]=hsin(a3);
  t.c[4]=hcos(a4); t.s[4]=hsin(a4); t.c[5]=hcos(a5); t.s[5]=hsin(a5);
  t.c[6]=hcos(a6); t.s[6]=hsin(a6); t.c[7]=hcos(a7); t.s[7]=hsin(a7);
  return t;
}

// ---------------- register-local butterflies ----------------
__device__ __forceinline__ void bfly_dif(float &ar, float &ai, float &br, float &bi,
                                         float wr, float wi) {
  float sr = ar + br, si = ai + bi;
  float dr = ar - br, di = ai - bi;
  ar = sr; ai = si;
  br = dr*wr - di*wi; bi = dr*wi + di*wr;
}
__device__ __forceinline__ void bfly_dit(float &ar, float &ai, float &br, float &bi,
                                         float wr, float wi) {
  float tr = br*wr - bi*wi, ti = br*wi + bi*wr;
  br = ar - tr; bi = ai - ti;
  ar = ar + tr; ai = ai + ti;
}

// Forward DIF cross-lane stage (twiddle = conj of precomputed).
#define FWD_XSTAGE(S, XCHG, CC, SS) { \
  const bool up = (lane & (S)) != 0; \
  const float sg = up ? -1.0f : 1.0f; \
  const float wr = up ? (CC) : 1.0f; \
  const float wi = up ? -(SS) : 0.0f; \
  _Pragma("unroll") for (int k = 0; k < 8; ++k) { \
    float rr = XCHG(xr[k]); float ri = XCHG(xi[k]); \
    float vr = fmaf(sg, xr[k], rr); float vi = fmaf(sg, xi[k], ri); \
    xr[k] = vr*wr - vi*wi; xi[k] = vr*wi + vi*wr; } }

// Inverse DIT cross-lane stage, select-free.
#define INV_XSTAGE(S, XCHG, CC, SS) { \
  const bool up = (lane & (S)) != 0; \
  const float wr = up ? (CC) : 1.0f; \
  const float wi = up ? (SS) : 0.0f; \
  const float sg = up ? -1.0f : 1.0f; \
  _Pragma("unroll") for (int k = 0; k < 8; ++k) { \
    float zr = xr[k]*wr - xi[k]*wi; \
    float zi = xr[k]*wi + xi[k]*wr; \
    float rr = XCHG(zr); float ri = XCHG(zi); \
    xr[k] = fmaf(sg, zr, rr); xi[k] = fmaf(sg, zi, ri); } }

// Forward DIF: natural in -> bit-reversed out (position n holds X[brev9(n)]).
__device__ __forceinline__ void wave_fft512_fwd(float xr[8], float xi[8], int lane,
                                                const Tw& t) {
  { // s=256
    float wr = t.c[0], wi = -t.s[0];
    const float rr8 = 0.70710678118654752f, ri8 = -0.70710678118654752f;
    #pragma unroll
    for (int k = 0; k < 4; ++k) {
      bfly_dif(xr[k], xi[k], xr[k+4], xi[k+4], wr, wi);
      float nr = wr*rr8 - wi*ri8, ni = wr*ri8 + wi*rr8;
      wr = nr; wi = ni;
    }
  }
  { // s=128
    float w0r = t.c[1], w0i = -t.s[1];
    float w1r = -t.s[1], w1i = -t.c[1];
    bfly_dif(xr[0], xi[0], xr[2], xi[2], w0r, w0i);
    bfly_dif(xr[1], xi[1], xr[3], xi[3], w1r, w1i);
    bfly_dif(xr[4], xi[4], xr[6], xi[6], w0r, w0i);
    bfly_dif(xr[5], xi[5], xr[7], xi[7], w1r, w1i);
  }
  { // s=64
    bfly_dif(xr[0], xi[0], xr[1], xi[1], t.c[2], -t.s[2]);
    bfly_dif(xr[2], xi[2], xr[3], xi[3], t.c[2], -t.s[2]);
    bfly_dif(xr[4], xi[4], xr[5], xi[5], t.c[2], -t.s[2]);
    bfly_dif(xr[6], xi[6], xr[7], xi[7], t.c[2], -t.s[2]);
  }
  FWD_XSTAGE(32, xs32, t.c[3], t.s[3])
  FWD_XSTAGE(16, xs16, t.c[4], t.s[4])
  FWD_XSTAGE(8,  xs8,  t.c[5], t.s[5])
  FWD_XSTAGE(4,  xs4,  t.c[6], t.s[6])
  FWD_XSTAGE(2,  xs2,  t.c[7], t.s[7])
  { // s=1
    const float sg = (lane & 1) ? -1.0f : 1.0f;
    #pragma unroll
    for (int k = 0; k < 8; ++k) {
      float rr = xs1(xr[k]); float ri = xs1(xi[k]);
      xr[k] = fmaf(sg, xr[k], rr); xi[k] = fmaf(sg, xi[k], ri);
    }
  }
}

// Inverse DIT: bit-reversed in -> natural out (unnormalized).
__device__ __forceinline__ void wave_fft512_inv(float xr[8], float xi[8], int lane,
                                                const Tw& t) {
  { // s=1
    const float sg = (lane & 1) ? -1.0f : 1.0f;
    #pragma unroll
    for (int k = 0; k < 8; ++k) {
      float rr = xs1(xr[k]); float ri = xs1(xi[k]);
      xr[k] = fmaf(sg, xr[k], rr); xi[k] = fmaf(sg, xi[k], ri);
    }
  }
  INV_XSTAGE(2,  xs2,  t.c[7], t.s[7])
  INV_XSTAGE(4,  xs4,  t.c[6], t.s[6])
  INV_XSTAGE(8,  xs8,  t.c[5], t.s[5])
  INV_XSTAGE(16, xs16, t.c[4], t.s[4])
  INV_XSTAGE(32, xs32, t.c[3], t.s[3])
  { // s=64
    bfly_dit(xr[0], xi[0], xr[1], xi[1], t.c[2], t.s[2]);
    bfly_dit(xr[2], xi[2], xr[3], xi[3], t.c[2], t.s[2]);
    bfly_dit(xr[4], xi[4], xr[5], xi[5], t.c[2], t.s[2]);
    bfly_dit(xr[6], xi[6], xr[7], xi[7], t.c[2], t.s[2]);
  }
  { // s=128
    float w0r = t.c[1], w0i = t.s[1];
    float w1r = -t.s[1], w1i = t.c[1];
    bfly_dit(xr[0], xi[0], xr[2], xi[2], w0r, w0i);
    bfly_dit(xr[1], xi[1], xr[3], xi[3], w1r, w1i);
    bfly_dit(xr[4], xi[4], xr[6], xi[6], w0r, w0i);
    bfly_dit(xr[5], xi[5], xr[7], xi[7], w1r, w1i);
  }
  { // s=256
    float wr = t.c[0], wi = t.s[0];
    const float rr8 = 0.70710678118654752f, ri8 = 0.70710678118654752f;
    #pragma unroll
    for (int k = 0; k < 4; ++k) {
      bfly_dit(xr[k], xi[k], xr[k+4], xi[k+4], wr, wi);
      float nr = wr*rr8 - wi*ri8, ni = wr*ri8 + wi*rr8;
      wr = nr; wi = ni;
    }
  }
}

// ---------------- kernels ----------------
__global__ void k_scatter(const int* __restrict__ idxx, const int* __restrict__ idxy,
                          const int* __restrict__ cid, int* __restrict__ W) {
  int p = blockIdx.x * 256 + threadIdx.x;
  int u = (idxx[p] + 256) & 511;
  int v = (idxy[p] + 256) & 511;
  atomicMax(&W[u * 512 + v], (p << 6) | cid[p]);
}

__global__ void k_pack(const int* __restrict__ W, int* __restrict__ pk) {
  int idx = blockIdx.x * 256 + threadIdx.x;
  if (idx >= 264 * 512) return;
  int j = idx >> 9, n = idx & 511;
  int out = (127 << 7) | 127;
  if (j < 257) {
    int v = (j == 256) ? 256 : brev9(2 * j);
    int u = brev9(n);
    int c1 = W[u * 512 + v];
    int c2 = W[((512 - u) & 511) * 512 + ((512 - v) & 511)];
    int a = (c1 < 0) ? 127 : (c1 & 63);
    int b = (c2 < 0) ? 127 : (c2 & 63);
    out = (b << 7) | a;
  }
  pk[j * 512 + n] = out;
}

// Two real rows per complex FFT: z = a + i*b; split A/B half-spectra, store both.
__global__ __launch_bounds__(512) void k_fwd_rows(const float* __restrict__ x,
                                                  float2* __restrict__ Yh) {
  __shared__ float zre[8 * 512], zim[8 * 512];
  int tid = threadIdx.x, w = tid >> 6, lane = tid & 63;
  int rp = blockIdx.x * 8 + w;                   // row pair 0..16383
  const float* rowA = x + (size_t)(2 * rp) * 512;
  const float* rowB = rowA + 512;
  Tw t = make_tw(lane);
  float xr[8], xi[8];
  #pragma unroll
  for (int k = 0; k < 8; ++k) { xr[k] = rowA[k*64 + lane]; xi[k] = rowB[k*64 + lane]; }
  wave_fft512_fwd(xr, xi, lane, t);
  float* zr = zre + w * 512;                     // wave-private LDS (DS is in-order per wave)
  float* zi = zim + w * 512;
  #pragma unroll
  for (int k = 0; k < 8; ++k) { zr[k*64 + lane] = xr[k]; zi[k*64 + lane] = xi[k]; }
  float2* orowA = Yh + (size_t)(2 * rp) * RS;
  float2* orowB = orowA + RS;
  #pragma unroll
  for (int k = 0; k < 4; ++k) {                  // stored index j, freq kf=brev9(2j)
    int j = k * 64 + lane;
    int n2 = 2 * j;
    int kf = brev9(n2);
    int m = brev9((512 - kf) & 511);             // mirror storage position (odd; 0 for j=0)
    float er = zr[n2], ei = zi[n2];
    float mr = zr[m],  mi = zi[m];
    orowA[j] = make_float2(0.5f * (er + mr), 0.5f * (ei - mi));
    orowB[j] = make_float2(0.5f * (ei + mi), 0.5f * (mr - er));
  }
  if (lane == 0) {                               // j=256 <- Z[256] at storage pos 1
    orowA[256] = make_float2(zr[1], 0.0f);
    orowB[256] = make_float2(zi[1], 0.0f);
  }
}

// Column FFT + symmetrized mask + inverse column FFT over 264 stored columns.
__global__ __launch_bounds__(512) void k_cols(float2* __restrict__ Yh,
                                              const int* __restrict__ pk,
                                              const float* __restrict__ pimp) {
  __shared__ float lre[8 * TS], lim[8 * TS];
  __shared__ float pilx[128];
  int tid = threadIdx.x;
  int b = blockIdx.x / 33, g = blockIdx.x % 33;
  float2* base = Yh + (size_t)b * 512 * RS + g * 8;
  #pragma unroll
  for (int rep = 0; rep < 4; ++rep) {
    int m = rep * 512 + tid;
    int i = m >> 2, cp = m & 3;
    float4 v = *(const float4*)(base + (size_t)i * RS + 2 * cp);
    lre[(2*cp)  *TS + i] = v.x; lim[(2*cp)  *TS + i] = v.y;
    lre[(2*cp+1)*TS + i] = v.z; lim[(2*cp+1)*TS + i] = v.w;
  }
  if (tid < 128) pilx[tid] = (tid < 64) ? pimp[b * 64 + tid] : 1.0f;
  int lane = tid & 63;
  Tw t = make_tw(lane);
  __syncthreads();
  int w = tid >> 6;
  float xr[8], xi[8];
  #pragma unroll
  for (int k = 0; k < 8; ++k) {
    xr[k] = lre[w*TS + k*64 + lane];
    xi[k] = lim[w*TS + k*64 + lane];
  }
  wave_fft512_fwd(xr, xi, lane, t);
  const int* cm = pk + (g * 8 + w) * 512;
  #pragma unroll
  for (int k = 0; k < 8; ++k) {
    int p = cm[k*64 + lane];
    float mm = 0.5f * (pilx[p & 127] + pilx[(p >> 7) & 127]) * INV_N2;
    xr[k] *= mm; xi[k] *= mm;
  }
  wave_fft512_inv(xr, xi, lane, t);
  #pragma unroll
  for (int k = 0; k < 8; ++k) {
    lre[w*TS + k*64 + lane] = xr[k];
    lim[w*TS + k*64 + lane] = xi[k];
  }
  __syncthreads();
  #pragma unroll
  for (int rep = 0; rep < 4; ++rep) {
    int m = rep * 512 + tid;
    int i = m >> 2, cp = m & 3;
    *(float4*)(base + (size_t)i * RS + 2 * cp) =
      make_float4(lre[(2*cp)*TS + i], lim[(2*cp)*TS + i],
                  lre[(2*cp+1)*TS + i], lim[(2*cp+1)*TS + i]);
  }
}

// Two real output rows per inverse FFT: C = A + i*B (Hermitian halves), re->2r, im->2r+1.
__global__ __launch_bounds__(512) void k_inv_rows(const float2* __restrict__ Yh,
                                                  float* __restrict__ out) {
  __shared__ float aRe[8*264], aIm[8*264], bRe[8*264], bIm[8*264];
  int tid = threadIdx.x, w = tid >> 6, lane = tid & 63;
  int rp = blockIdx.x * 8 + w;
  const float2* rowA = Yh + (size_t)(2 * rp) * RS;
  const float2* rowB = rowA + RS;
  Tw t = make_tw(lane);
  float* ar_ = aRe + w*264; float* ai_ = aIm + w*264;
  float* br_ = bRe + w*264; float* bi_ = bIm + w*264;
  #pragma unroll
  for (int k2 = 0; k2 < 5; ++k2) {               // wave-private staging
    int idx = k2 * 64 + lane;
    if (idx < 257) {
      float2 va = rowA[idx]; ar_[idx] = va.x; ai_[idx] = va.y;
      float2 vb = rowB[idx]; br_[idx] = vb.x; bi_[idx] = vb.y;
    }
  }
  float xr[8], xi[8];
  #pragma unroll
  for (int k = 0; k < 8; ++k) {
    int n = k * 64 + lane;
    int v9 = brev9(n);
    int j2 = brev9((512 - v9) & 511) >> 1;
    bool oddx = (n & 1) && (n != 1);
    int j = (n & 1) ? ((n == 1) ? 256 : j2) : (n >> 1);
    float s = oddx ? -1.0f : 1.0f;
    float ar = ar_[j], ai = ai_[j], br = br_[j], bi = bi_[j];
    xr[k] = ar - s * bi;                         // C = A_full + i*B_full
    xi[k] = fmaf(s, ai, br);
  }
  wave_fft512_inv(xr, xi, lane, t);
  float* orowA = out + (size_t)(2 * rp) * 512;
  float* orowB = orowA + 512;
  #pragma unroll
  for (int k = 0; k < 8; ++k) {
    orowA[k*64 + lane] = xr[k];
    orowB[k*64 + lane] = xi[k];
  }
}

extern "C" void kernel_launch(void* const* d_in, const int* in_sizes, int n_in,
                              void* d_out, int out_size, void* d_ws, size_t ws_size,
                              hipStream_t stream) {
  const float* x    = (const float*)d_in[0];
  const float* pimp = (const float*)d_in[1];
  const int* idxx   = (const int*)d_in[2];
  const int* idxy   = (const int*)d_in[3];
  const int* cid    = (const int*)d_in[4];

  float2* Yh = (float2*)d_ws;                                    // 66 MB
  int* W  = (int*)((char*)d_ws + YH_F2 * sizeof(float2));        // 1 MB
  int* pk = W + 512 * 512;                                       // 0.53 MB

  hipMemsetAsync(W, 0xFF, 512 * 512 * sizeof(int), stream);
  k_scatter  <<<1024, 256, 0, stream>>>(idxx, idxy, cid, W);
  k_pack     <<<(264 * 512 + 255) / 256, 256, 0, stream>>>(W, pk);
  k_fwd_rows <<<2048, 512, 0, stream>>>(x, Yh);
  k_cols     <<<64 * 33, 512, 0, stream>>>(Yh, pk, pimp);
  k_inv_rows <<<2048, 512, 0, stream>>>(Yh, (float*)d_out);
}

// Round 5
// 200.672 us; speedup vs baseline: 1.5420x; 1.0663x over previous
//
#include <hip/hip_runtime.h>

#define INV_N2 (1.0f/262144.0f)
#define TP 17                         // LDS row-tile stride (16 rows + 1 pad)
#define YT_B ((size_t)(264 * 512))    // Yt batch stride in float2 (264 cols x 512 rows)

typedef unsigned u32x2 __attribute__((ext_vector_type(2)));

__device__ __forceinline__ int brev9(int v) { return (int)(__brev((unsigned)v) >> 23); }
__device__ __forceinline__ float hsin(float rev) { return __builtin_amdgcn_sinf(rev); }
__device__ __forceinline__ float hcos(float rev) { return __builtin_amdgcn_cosf(rev); }

// ---------------- cross-lane exchange ----------------
template<int CTRL>
__device__ __forceinline__ float xdpp(float x) {
  int v = __float_as_int(x);
  return __int_as_float(__builtin_amdgcn_update_dpp(v, v, CTRL, 0xF, 0xF, true));
}
__device__ __forceinline__ float xs1(float x) { return xdpp<0xB1>(x); }   // quad_perm [1,0,3,2]
__device__ __forceinline__ float xs2(float x) { return xdpp<0x4E>(x); }   // quad_perm [2,3,0,1]
__device__ __forceinline__ float xs8(float x) { return xdpp<0x128>(x); }  // row_ror:8
__device__ __forceinline__ float xs4(float x) {
  return __int_as_float(__builtin_amdgcn_ds_swizzle(__float_as_int(x), 0x101F));
}
// Swap-based exchanges: return BOTH halves (lo = value at lane&~S, hi = value at lane|S).
__device__ __forceinline__ void swp16(float x, float &lo, float &hi) {
#if __has_builtin(__builtin_amdgcn_permlane16_swap)
  u32x2 r = __builtin_amdgcn_permlane16_swap(__float_as_uint(x), __float_as_uint(x), false, false);
  lo = __uint_as_float(r[0]); hi = __uint_as_float(r[1]);
#else
  float p = __int_as_float(__builtin_amdgcn_ds_swizzle(__float_as_int(x), 0x401F));
  bool up = (threadIdx.x & 16) != 0;
  lo = up ? p : x; hi = up ? x : p;
#endif
}
__device__ __forceinline__ void swp32(float x, float &lo, float &hi) {
#if __has_builtin(__builtin_amdgcn_permlane32_swap)
  u32x2 r = __builtin_amdgcn_permlane32_swap(__float_as_uint(x), __float_as_uint(x), false, false);
  lo = __uint_as_float(r[0]); hi = __uint_as_float(r[1]);
#else
  float p = __shfl_xor(x, 32, 64);
  bool up = (threadIdx.x & 32) != 0;
  lo = up ? p : x; hi = up ? x : p;
#endif
}

// ---------------- per-lane stage twiddles ----------------
struct Tw { float c[8], s[8]; };
__device__ __forceinline__ Tw make_tw(int lane) {
  Tw t;
  float a0 = (float)lane        * (1.0f/512.0f);
  float a1 = (float)lane        * (1.0f/256.0f);
  float a2 = (float)lane        * (1.0f/128.0f);
  float a3 = (float)(lane & 31) * (1.0f/64.0f);
  float a4 = (float)(lane & 15) * (1.0f/32.0f);
  float a5 = (float)(lane & 7)  * (1.0f/16.0f);
  float a6 = (float)(lane & 3)  * (1.0f/8.0f);
  float a7 = (float)(lane & 1)  * (1.0f/4.0f);
  t.c[0]=hcos(a0); t.s[0]=hsin(a0); t.c[1]=hcos(a1); t.s[1]=hsin(a1);
  t.c[2]=hcos(a2); t.s[2]=hsin(a2); t.c[3]=hcos(a3); t.s[3]=hsin(a3);
  t.c[4]=hcos(a4); t.s[4]=hsin(a4); t.c[5]=hcos(a5); t.s[5]=hsin(a5);
  t.c[6]=hcos(a6); t.s[6]=hsin(a6); t.c[7]=hcos(a7); t.s[7]=hsin(a7);
  return t;
}

// ---------------- register-local butterflies ----------------
__device__ __forceinline__ void bfly_dif(float &ar, float &ai, float &br, float &bi,
                                         float wr, float wi) {
  float sr = ar + br, si = ai + bi;
  float dr = ar - br, di = ai - bi;
  ar = sr; ai = si;
  br = dr*wr - di*wi; bi = dr*wi + di*wr;
}
__device__ __forceinline__ void bfly_dit(float &ar, float &ai, float &br, float &bi,
                                         float wr, float wi) {
  float tr = br*wr - bi*wi, ti = br*wi + bi*wr;
  br = ar - tr; bi = ai - ti;
  ar = ar + tr; ai = ai + ti;
}

// Forward DIF cross-lane stage (partner via single-value exchange).
#define FWD_XSTAGE(S, XCHG, CC, SS) { \
  const bool up = (lane & (S)) != 0; \
  const float sg = up ? -1.0f : 1.0f; \
  const float wr = up ? (CC) : 1.0f; \
  const float wi = up ? -(SS) : 0.0f; \
  _Pragma("unroll") for (int k = 0; k < 8; ++k) { \
    float rr = XCHG(xr[k]); float ri = XCHG(xi[k]); \
    float vr = fmaf(sg, xr[k], rr); float vi = fmaf(sg, xi[k], ri); \
    xr[k] = vr*wr - vi*wi; xi[k] = vr*wi + vi*wr; } }

// Forward DIF cross-lane stage via half-swap (select-free combine).
#define FWD_SWSTAGE(S, SWP, CC, SS) { \
  const bool up = (lane & (S)) != 0; \
  const float sg = up ? -1.0f : 1.0f; \
  const float wr = up ? (CC) : 1.0f; \
  const float wi = up ? -(SS) : 0.0f; \
  _Pragma("unroll") for (int k = 0; k < 8; ++k) { \
    float lr, hr, li, hi2; \
    SWP(xr[k], lr, hr); SWP(xi[k], li, hi2); \
    float vr = fmaf(sg, hr, lr); float vi = fmaf(sg, hi2, li); \
    xr[k] = vr*wr - vi*wi; xi[k] = vr*wi + vi*wr; } }

// Inverse DIT cross-lane stage, select-free (twiddle own value first).
#define INV_XSTAGE(S, XCHG, CC, SS) { \
  const bool up = (lane & (S)) != 0; \
  const float wr = up ? (CC) : 1.0f; \
  const float wi = up ? (SS) : 0.0f; \
  const float sg = up ? -1.0f : 1.0f; \
  _Pragma("unroll") for (int k = 0; k < 8; ++k) { \
    float zr = xr[k]*wr - xi[k]*wi; \
    float zi = xr[k]*wi + xi[k]*wr; \
    float rr = XCHG(zr); float ri = XCHG(zi); \
    xr[k] = fmaf(sg, zr, rr); xi[k] = fmaf(sg, zi, ri); } }

// Inverse DIT cross-lane stage via half-swap.
#define INV_SWSTAGE(S, SWP, CC, SS) { \
  const bool up = (lane & (S)) != 0; \
  const float wr = up ? (CC) : 1.0f; \
  const float wi = up ? (SS) : 0.0f; \
  const float sg = up ? -1.0f : 1.0f; \
  _Pragma("unroll") for (int k = 0; k < 8; ++k) { \
    float zr = xr[k]*wr - xi[k]*wi; \
    float zi = xr[k]*wi + xi[k]*wr; \
    float lr, hr, li, hi2; \
    SWP(zr, lr, hr); SWP(zi, li, hi2); \
    xr[k] = fmaf(sg, hr, lr); xi[k] = fmaf(sg, hi2, li); } }

// Forward DIF: natural in -> bit-reversed out (position n holds X[brev9(n)]).
__device__ __forceinline__ void wave_fft512_fwd(float xr[8], float xi[8], int lane,
                                                const Tw& t) {
  { // s=256
    float wr = t.c[0], wi = -t.s[0];
    const float rr8 = 0.70710678118654752f, ri8 = -0.70710678118654752f;
    #pragma unroll
    for (int k = 0; k < 4; ++k) {
      bfly_dif(xr[k], xi[k], xr[k+4], xi[k+4], wr, wi);
      float nr = wr*rr8 - wi*ri8, ni = wr*ri8 + wi*rr8;
      wr = nr; wi = ni;
    }
  }
  { // s=128
    float w0r = t.c[1], w0i = -t.s[1];
    float w1r = -t.s[1], w1i = -t.c[1];
    bfly_dif(xr[0], xi[0], xr[2], xi[2], w0r, w0i);
    bfly_dif(xr[1], xi[1], xr[3], xi[3], w1r, w1i);
    bfly_dif(xr[4], xi[4], xr[6], xi[6], w0r, w0i);
    bfly_dif(xr[5], xi[5], xr[7], xi[7], w1r, w1i);
  }
  { // s=64
    bfly_dif(xr[0], xi[0], xr[1], xi[1], t.c[2], -t.s[2]);
    bfly_dif(xr[2], xi[2], xr[3], xi[3], t.c[2], -t.s[2]);
    bfly_dif(xr[4], xi[4], xr[5], xi[5], t.c[2], -t.s[2]);
    bfly_dif(xr[6], xi[6], xr[7], xi[7], t.c[2], -t.s[2]);
  }
  FWD_SWSTAGE(32, swp32, t.c[3], t.s[3])
  FWD_SWSTAGE(16, swp16, t.c[4], t.s[4])
  FWD_XSTAGE(8,  xs8,  t.c[5], t.s[5])
  FWD_XSTAGE(4,  xs4,  t.c[6], t.s[6])
  FWD_XSTAGE(2,  xs2,  t.c[7], t.s[7])
  { // s=1
    const float sg = (lane & 1) ? -1.0f : 1.0f;
    #pragma unroll
    for (int k = 0; k < 8; ++k) {
      float rr = xs1(xr[k]); float ri = xs1(xi[k]);
      xr[k] = fmaf(sg, xr[k], rr); xi[k] = fmaf(sg, xi[k], ri);
    }
  }
}

// Inverse DIT: bit-reversed in -> natural out (unnormalized).
__device__ __forceinline__ void wave_fft512_inv(float xr[8], float xi[8], int lane,
                                                const Tw& t) {
  { // s=1
    const float sg = (lane & 1) ? -1.0f : 1.0f;
    #pragma unroll
    for (int k = 0; k < 8; ++k) {
      float rr = xs1(xr[k]); float ri = xs1(xi[k]);
      xr[k] = fmaf(sg, xr[k], rr); xi[k] = fmaf(sg, xi[k], ri);
    }
  }
  INV_XSTAGE(2,  xs2,  t.c[7], t.s[7])
  INV_XSTAGE(4,  xs4,  t.c[6], t.s[6])
  INV_XSTAGE(8,  xs8,  t.c[5], t.s[5])
  INV_SWSTAGE(16, swp16, t.c[4], t.s[4])
  INV_SWSTAGE(32, swp32, t.c[3], t.s[3])
  { // s=64
    bfly_dit(xr[0], xi[0], xr[1], xi[1], t.c[2], t.s[2]);
    bfly_dit(xr[2], xi[2], xr[3], xi[3], t.c[2], t.s[2]);
    bfly_dit(xr[4], xi[4], xr[5], xi[5], t.c[2], t.s[2]);
    bfly_dit(xr[6], xi[6], xr[7], xi[7], t.c[2], t.s[2]);
  }
  { // s=128
    float w0r = t.c[1], w0i = t.s[1];
    float w1r = -t.s[1], w1i = t.c[1];
    bfly_dit(xr[0], xi[0], xr[2], xi[2], w0r, w0i);
    bfly_dit(xr[1], xi[1], xr[3], xi[3], w1r, w1i);
    bfly_dit(xr[4], xi[4], xr[6], xi[6], w0r, w0i);
    bfly_dit(xr[5], xi[5], xr[7], xi[7], w1r, w1i);
  }
  { // s=256
    float wr = t.c[0], wi = t.s[0];
    const float rr8 = 0.70710678118654752f, ri8 = 0.70710678118654752f;
    #pragma unroll
    for (int k = 0; k < 4; ++k) {
      bfly_dit(xr[k], xi[k], xr[k+4], xi[k+4], wr, wi);
      float nr = wr*rr8 - wi*ri8, ni = wr*ri8 + wi*rr8;
      wr = nr; wi = ni;
    }
  }
}

// ---------------- kernels ----------------
__global__ void k_scatter(const int* __restrict__ idxx, const int* __restrict__ idxy,
                          const int* __restrict__ cid, int* __restrict__ W) {
  int p = blockIdx.x * 256 + threadIdx.x;
  int u = (idxx[p] + 256) & 511;
  int v = (idxy[p] + 256) & 511;
  atomicMax(&W[u * 512 + v], (p << 6) | cid[p]);
}

__global__ void k_pack(const int* __restrict__ W, int* __restrict__ pk) {
  int idx = blockIdx.x * 256 + threadIdx.x;
  if (idx >= 264 * 512) return;
  int j = idx >> 9, n = idx & 511;
  int out = (127 << 7) | 127;
  if (j < 257) {
    int v = (j == 256) ? 256 : brev9(2 * j);
    int u = brev9(n);
    int c1 = W[u * 512 + v];
    int c2 = W[((512 - u) & 511) * 512 + ((512 - v) & 511)];
    int a = (c1 < 0) ? 127 : (c1 & 63);
    int b = (c2 < 0) ? 127 : (c2 & 63);
    out = (b << 7) | a;
  }
  pk[j * 512 + n] = out;
}

// Two real rows per complex FFT; output TRANSPOSED: Yt[b][j][r].
// Block = 16 consecutive rows (8 row-pairs, one per wave) of one batch.
__global__ __launch_bounds__(512) void k_fwd_rows(const float* __restrict__ x,
                                                  float2* __restrict__ Yt) {
  __shared__ float sm[2 * 264 * TP];             // 35.9 KB; z-region aliased pre-barrier
  float* tR = sm;
  float* tI = sm + 264 * TP;
  int tid = threadIdx.x, w = tid >> 6, lane = tid & 63;
  int R0 = blockIdx.x * 16;
  int bb = R0 >> 9, r0 = R0 & 511;
  const float* rowA = x + (size_t)(R0 + 2 * w) * 512;
  const float* rowB = rowA + 512;
  Tw t = make_tw(lane);
  float xr[8], xi[8];
  #pragma unroll
  for (int k = 0; k < 8; ++k) { xr[k] = rowA[k*64 + lane]; xi[k] = rowB[k*64 + lane]; }
  wave_fft512_fwd(xr, xi, lane, t);
  float* zr = sm + w * 1024;                     // wave-private scratch (in-order DS)
  float* zi = zr + 512;
  #pragma unroll
  for (int k = 0; k < 8; ++k) { zr[k*64 + lane] = xr[k]; zi[k*64 + lane] = xi[k]; }
  float ar[4], ai[4], br[4], bi[4];
  #pragma unroll
  for (int k = 0; k < 4; ++k) {                  // split A/B half-spectra (wave-private)
    int j = k * 64 + lane;
    int n2 = 2 * j;
    int kf = brev9(n2);
    int m = brev9((512 - kf) & 511);
    float er = zr[n2], ei = zi[n2];
    float mr = zr[m],  mi = zi[m];
    ar[k] = 0.5f * (er + mr); ai[k] = 0.5f * (ei - mi);
    br[k] = 0.5f * (ei + mi); bi[k] = 0.5f * (mr - er);
  }
  float a256 = zr[1], b256 = zi[1];
  __syncthreads();                               // all waves done with z-scratch
  #pragma unroll
  for (int k = 0; k < 4; ++k) {                  // tile[j][rr]: A at rr=2w, B at rr=2w+1
    int j = k * 64 + lane;
    tR[j*TP + 2*w]     = ar[k]; tI[j*TP + 2*w]     = ai[k];
    tR[j*TP + 2*w + 1] = br[k]; tI[j*TP + 2*w + 1] = bi[k];
  }
  if (lane == 0) {
    tR[256*TP + 2*w]     = a256; tI[256*TP + 2*w]     = 0.0f;
    tR[256*TP + 2*w + 1] = b256; tI[256*TP + 2*w + 1] = 0.0f;
  }
  __syncthreads();
  #pragma unroll
  for (int rep = 0; rep < 9; ++rep) {            // 128B-contiguous chunks per column
    int e = rep * 512 + tid;
    int j = e >> 4, rr = e & 15;
    if (j < 257)
      Yt[((size_t)bb * 264 + j) * 512 + r0 + rr] =
        make_float2(tR[j*TP + rr], tI[j*TP + rr]);
  }
}

// Column FFT + symmetrized mask + inverse column FFT. NO tile: Yt is column-contiguous.
__global__ __launch_bounds__(512) void k_cols(float2* __restrict__ Yt,
                                              const int* __restrict__ pk,
                                              const float* __restrict__ pimp) {
  __shared__ float pilx[128];
  int tid = threadIdx.x;
  int b = blockIdx.x / 33, g = blockIdx.x % 33;
  if (tid < 128) pilx[tid] = (tid < 64) ? pimp[b * 64 + tid] : 1.0f;
  int w = tid >> 6, lane = tid & 63;
  int j = g * 8 + w;
  float2* col = Yt + ((size_t)b * 264 + j) * 512;
  const int* cm = pk + j * 512;
  int pcm[8];
  float xr[8], xi[8];
  #pragma unroll
  for (int k = 0; k < 8; ++k) {                  // coalesced float2 loads + pk prefetch
    float2 v = col[k*64 + lane];
    xr[k] = v.x; xi[k] = v.y;
    pcm[k] = cm[k*64 + lane];
  }
  Tw t = make_tw(lane);
  wave_fft512_fwd(xr, xi, lane, t);
  __syncthreads();                               // pilx ready (hidden behind FFT)
  #pragma unroll
  for (int k = 0; k < 8; ++k) {
    int p = pcm[k];
    float mm = 0.5f * (pilx[p & 127] + pilx[(p >> 7) & 127]) * INV_N2;
    xr[k] *= mm; xi[k] *= mm;
  }
  wave_fft512_inv(xr, xi, lane, t);
  #pragma unroll
  for (int k = 0; k < 8; ++k) col[k*64 + lane] = make_float2(xr[k], xi[k]);
}

// Hermitian mirror + inverse row FFT -> two real rows per wave.
__global__ __launch_bounds__(512) void k_inv_rows(const float2* __restrict__ Yt,
                                                  float* __restrict__ out) {
  __shared__ float tR[264 * TP], tI[264 * TP];
  int tid = threadIdx.x, w = tid >> 6, lane = tid & 63;
  int R0 = blockIdx.x * 16;
  int bb = R0 >> 9, r0 = R0 & 511;
  #pragma unroll
  for (int rep = 0; rep < 9; ++rep) {            // coalesced 128B-chunk tile load
    int e = rep * 512 + tid;
    int j = e >> 4, rr = e & 15;
    if (j < 257) {
      float2 v = Yt[((size_t)bb * 264 + j) * 512 + r0 + rr];
      tR[j*TP + rr] = v.x; tI[j*TP + rr] = v.y;
    }
  }
  Tw t = make_tw(lane);
  __syncthreads();
  float xr[8], xi[8];
  #pragma unroll
  for (int k = 0; k < 8; ++k) {                  // C = A + i*B with Hermitian mirror
    int n = k * 64 + lane;
    int v9 = brev9(n);
    int j2 = brev9((512 - v9) & 511) >> 1;
    bool oddx = (n & 1) && (n != 1);
    int j = (n & 1) ? ((n == 1) ? 256 : j2) : (n >> 1);
    float s = oddx ? -1.0f : 1.0f;
    float ar = tR[j*TP + 2*w],     ai = tI[j*TP + 2*w];
    float br = tR[j*TP + 2*w + 1], bi = tI[j*TP + 2*w + 1];
    xr[k] = ar - s * bi;
    xi[k] = fmaf(s, ai, br);
  }
  wave_fft512_inv(xr, xi, lane, t);
  float* orowA = out + (size_t)(R0 + 2 * w) * 512;
  float* orowB = orowA + 512;
  #pragma unroll
  for (int k = 0; k < 8; ++k) {
    orowA[k*64 + lane] = xr[k];
    orowB[k*64 + lane] = xi[k];
  }
}

extern "C" void kernel_launch(void* const* d_in, const int* in_sizes, int n_in,
                              void* d_out, int out_size, void* d_ws, size_t ws_size,
                              hipStream_t stream) {
  const float* x    = (const float*)d_in[0];
  const float* pimp = (const float*)d_in[1];
  const int* idxx   = (const int*)d_in[2];
  const int* idxy   = (const int*)d_in[3];
  const int* cid    = (const int*)d_in[4];

  float2* Yt = (float2*)d_ws;                                    // 64*264*512*8 = 69.2 MB
  int* W  = (int*)((char*)d_ws + (size_t)64 * YT_B * sizeof(float2)); // 1 MB
  int* pk = W + 512 * 512;                                       // 0.54 MB

  hipMemsetAsync(W, 0xFF, 512 * 512 * sizeof(int), stream);
  k_scatter  <<<1024, 256, 0, stream>>>(idxx, idxy, cid, W);
  k_pack     <<<(264 * 512 + 255) / 256, 256, 0, stream>>>(W, pk);
  k_fwd_rows <<<2048, 512, 0, stream>>>(x, Yt);
  k_cols     <<<64 * 33, 512, 0, stream>>>(Yt, pk, pimp);
  k_inv_rows <<<2048, 512, 0, stream>>>(Yt, (float*)d_out);
}

// Round 6
// 199.788 us; speedup vs baseline: 1.5488x; 1.0044x over previous
//
#include <hip/hip_runtime.h>

#define INV_N2 (1.0f/262144.0f)
#define HALF_INV (0.5f*INV_N2)
#define TP 17                         // LDS row-tile stride (16 rows + 1 pad)
#define YT_B ((size_t)(264 * 512))    // Yt batch stride in float2

typedef unsigned u32x2 __attribute__((ext_vector_type(2)));
typedef float v2f __attribute__((ext_vector_type(2)));

__device__ __forceinline__ v2f v2(float a, float b) { v2f r; r.x = a; r.y = b; return r; }
__device__ __forceinline__ int brev9(int v) { return (int)(__brev((unsigned)v) >> 23); }
__device__ __forceinline__ float hsin(float rev) { return __builtin_amdgcn_sinf(rev); }
__device__ __forceinline__ float hcos(float rev) { return __builtin_amdgcn_cosf(rev); }

// ---------------- cross-lane exchange ----------------
template<int CTRL>
__device__ __forceinline__ float xdpp(float x) {
  int v = __float_as_int(x);
  return __int_as_float(__builtin_amdgcn_update_dpp(v, v, CTRL, 0xF, 0xF, true));
}
__device__ __forceinline__ float xs1(float x) { return xdpp<0xB1>(x); }   // quad_perm [1,0,3,2]
__device__ __forceinline__ float xs2(float x) { return xdpp<0x4E>(x); }   // quad_perm [2,3,0,1]
__device__ __forceinline__ float xs8(float x) { return xdpp<0x128>(x); }  // row_ror:8
__device__ __forceinline__ float xs4(float x) {
  return __int_as_float(__builtin_amdgcn_ds_swizzle(__float_as_int(x), 0x101F));
}
// Swap exchanges: return BOTH halves (lo = value at lane&~S, hi = value at lane|S).
__device__ __forceinline__ void swp16(float x, float &lo, float &hi) {
#if __has_builtin(__builtin_amdgcn_permlane16_swap)
  u32x2 r = __builtin_amdgcn_permlane16_swap(__float_as_uint(x), __float_as_uint(x), false, false);
  lo = __uint_as_float(r[0]); hi = __uint_as_float(r[1]);
#else
  float p = __int_as_float(__builtin_amdgcn_ds_swizzle(__float_as_int(x), 0x401F));
  bool up = (threadIdx.x & 16) != 0;
  lo = up ? p : x; hi = up ? x : p;
#endif
}
__device__ __forceinline__ void swp32(float x, float &lo, float &hi) {
#if __has_builtin(__builtin_amdgcn_permlane32_swap)
  u32x2 r = __builtin_amdgcn_permlane32_swap(__float_as_uint(x), __float_as_uint(x), false, false);
  lo = __uint_as_float(r[0]); hi = __uint_as_float(r[1]);
#else
  float p = __shfl_xor(x, 32, 64);
  bool up = (threadIdx.x & 32) != 0;
  lo = up ? p : x; hi = up ? x : p;
#endif
}

// ---------------- per-lane stage twiddles ----------------
struct Tw { float c[8], s[8]; };
__device__ __forceinline__ Tw make_tw(int lane) {
  Tw t;
  float a0 = (float)lane        * (1.0f/512.0f);
  float a1 = (float)lane        * (1.0f/256.0f);
  float a2 = (float)lane        * (1.0f/128.0f);
  float a3 = (float)(lane & 31) * (1.0f/64.0f);
  float a4 = (float)(lane & 15) * (1.0f/32.0f);
  float a5 = (float)(lane & 7)  * (1.0f/16.0f);
  float a6 = (float)(lane & 3)  * (1.0f/8.0f);
  float a7 = (float)(lane & 1)  * (1.0f/4.0f);
  t.c[0]=hcos(a0); t.s[0]=hsin(a0); t.c[1]=hcos(a1); t.s[1]=hsin(a1);
  t.c[2]=hcos(a2); t.s[2]=hsin(a2); t.c[3]=hcos(a3); t.s[3]=hsin(a3);
  t.c[4]=hcos(a4); t.s[4]=hsin(a4); t.c[5]=hcos(a5); t.s[5]=hsin(a5);
  t.c[6]=hcos(a6); t.s[6]=hsin(a6); t.c[7]=hcos(a7); t.s[7]=hsin(a7);
  return t;
}

// ---------------- packed cross-lane stage macros ----------------
// State: v2f Xr[4], Xi[4]; element n = (2j+h)*64 + lane (h = vector half).
// Forward DIF, single-value exchange (s=8,4,2): out = (R + sg*X) * W.
#define FWD_PK_XS(S, XCHG, CC, SS) { \
  const bool up = (lane & (S)) != 0; \
  const float sg = up ? -1.0f : 1.0f; \
  const float wr = up ? (CC) : 1.0f; \
  const float wi = up ? -(SS) : 0.0f; \
  const v2f sgv = v2(sg,sg), wrv = v2(wr,wr), wiv = v2(wi,wi); \
  _Pragma("unroll") for (int j = 0; j < 4; ++j) { \
    v2f Rr = v2(XCHG(Xr[j].x), XCHG(Xr[j].y)); \
    v2f Ri = v2(XCHG(Xi[j].x), XCHG(Xi[j].y)); \
    v2f vr = sgv*Xr[j] + Rr; v2f vi = sgv*Xi[j] + Ri; \
    Xr[j] = vr*wrv - vi*wiv; Xi[j] = vr*wiv + vi*wrv; } }

// Forward DIF via half-swap (s=32,16).
#define FWD_PK_SW(S, SWP, CC, SS) { \
  const bool up = (lane & (S)) != 0; \
  const float sg = up ? -1.0f : 1.0f; \
  const float wr = up ? (CC) : 1.0f; \
  const float wi = up ? -(SS) : 0.0f; \
  const v2f sgv = v2(sg,sg), wrv = v2(wr,wr), wiv = v2(wi,wi); \
  _Pragma("unroll") for (int j = 0; j < 4; ++j) { \
    float l0,h0,l1,h1; \
    SWP(Xr[j].x,l0,h0); SWP(Xr[j].y,l1,h1); \
    v2f Lr = v2(l0,l1), Hr = v2(h0,h1); \
    SWP(Xi[j].x,l0,h0); SWP(Xi[j].y,l1,h1); \
    v2f Li = v2(l0,l1), Hi = v2(h0,h1); \
    v2f vr = sgv*Hr + Lr; v2f vi = sgv*Hi + Li; \
    Xr[j] = vr*wrv - vi*wiv; Xi[j] = vr*wiv + vi*wrv; } }

// Inverse DIT, single-value exchange: Z = X*W, exchange, out = R + sg*Z.
#define INV_PK_XS(S, XCHG, CC, SS) { \
  const bool up = (lane & (S)) != 0; \
  const float wr = up ? (CC) : 1.0f; \
  const float wi = up ? (SS) : 0.0f; \
  const float sg = up ? -1.0f : 1.0f; \
  const v2f sgv = v2(sg,sg), wrv = v2(wr,wr), wiv = v2(wi,wi); \
  _Pragma("unroll") for (int j = 0; j < 4; ++j) { \
    v2f Zr = Xr[j]*wrv - Xi[j]*wiv; \
    v2f Zi = Xr[j]*wiv + Xi[j]*wrv; \
    v2f Rr = v2(XCHG(Zr.x), XCHG(Zr.y)); \
    v2f Ri = v2(XCHG(Zi.x), XCHG(Zi.y)); \
    Xr[j] = sgv*Zr + Rr; Xi[j] = sgv*Zi + Ri; } }

// Inverse DIT via half-swap.
#define INV_PK_SW(S, SWP, CC, SS) { \
  const bool up = (lane & (S)) != 0; \
  const float wr = up ? (CC) : 1.0f; \
  const float wi = up ? (SS) : 0.0f; \
  const float sg = up ? -1.0f : 1.0f; \
  const v2f sgv = v2(sg,sg), wrv = v2(wr,wr), wiv = v2(wi,wi); \
  _Pragma("unroll") for (int j = 0; j < 4; ++j) { \
    v2f Zr = Xr[j]*wrv - Xi[j]*wiv; \
    v2f Zi = Xr[j]*wiv + Xi[j]*wrv; \
    float l0,h0,l1,h1; \
    SWP(Zr.x,l0,h0); SWP(Zr.y,l1,h1); \
    v2f Lr = v2(l0,l1), Hr = v2(h0,h1); \
    SWP(Zi.x,l0,h0); SWP(Zi.y,l1,h1); \
    v2f Li = v2(l0,l1), Hi = v2(h0,h1); \
    Xr[j] = sgv*Hr + Lr; Xi[j] = sgv*Hi + Li; } }

// Forward DIF: natural in -> bit-reversed out.
__device__ __forceinline__ void wave_fft512_fwd(v2f Xr[4], v2f Xi[4], int lane,
                                                const Tw& t) {
  { // s=256: packed per-k twiddles; Tr1=Ti0, Ti1=-Tr0
    const float c8 = 0.70710678118654752f;
    float wr = t.c[0], wi = -t.s[0];
    float w1r = c8*(wr + wi), w1i = c8*(wi - wr);
    v2f Tr0 = v2(wr, w1r), Ti0 = v2(wi, w1i);
    { v2f Sr = Xr[0]+Xr[2], Si = Xi[0]+Xi[2];
      v2f Dr = Xr[0]-Xr[2], Di = Xi[0]-Xi[2];
      Xr[0] = Sr; Xi[0] = Si;
      Xr[2] = Dr*Tr0 - Di*Ti0; Xi[2] = Dr*Ti0 + Di*Tr0; }
    { v2f Sr = Xr[1]+Xr[3], Si = Xi[1]+Xi[3];
      v2f Dr = Xr[1]-Xr[3], Di = Xi[1]-Xi[3];
      Xr[1] = Sr; Xi[1] = Si;
      Xr[3] = Dr*Ti0 + Di*Tr0; Xi[3] = Di*Ti0 - Dr*Tr0; }
  }
  { // s=128: T = {w0, w1}, w0=(c1,-s1), w1=(-s1,-c1)
    v2f Tr = v2(t.c[1], -t.s[1]), Ti = v2(-t.s[1], -t.c[1]);
    #pragma unroll
    for (int j = 0; j < 4; j += 2) {
      v2f Sr = Xr[j]+Xr[j+1], Si = Xi[j]+Xi[j+1];
      v2f Dr = Xr[j]-Xr[j+1], Di = Xi[j]-Xi[j+1];
      Xr[j] = Sr; Xi[j] = Si;
      Xr[j+1] = Dr*Tr - Di*Ti; Xi[j+1] = Dr*Ti + Di*Tr;
    }
  }
  { // s=64: intra-pair, scalar (v2f halves are separate VGPRs)
    float wr = t.c[2], wi = -t.s[2];
    #pragma unroll
    for (int j = 0; j < 4; ++j) {
      float sr = Xr[j].x + Xr[j].y, si = Xi[j].x + Xi[j].y;
      float dr = Xr[j].x - Xr[j].y, di = Xi[j].x - Xi[j].y;
      Xr[j] = v2(sr, dr*wr - di*wi);
      Xi[j] = v2(si, dr*wi + di*wr);
    }
  }
  FWD_PK_SW(32, swp32, t.c[3], t.s[3])
  FWD_PK_SW(16, swp16, t.c[4], t.s[4])
  FWD_PK_XS(8,  xs8,  t.c[5], t.s[5])
  FWD_PK_XS(4,  xs4,  t.c[6], t.s[6])
  FWD_PK_XS(2,  xs2,  t.c[7], t.s[7])
  { // s=1: trivial twiddle
    const float sg = (lane & 1) ? -1.0f : 1.0f;
    const v2f sgv = v2(sg, sg);
    #pragma unroll
    for (int j = 0; j < 4; ++j) {
      v2f Rr = v2(xs1(Xr[j].x), xs1(Xr[j].y));
      v2f Ri = v2(xs1(Xi[j].x), xs1(Xi[j].y));
      Xr[j] = sgv*Xr[j] + Rr; Xi[j] = sgv*Xi[j] + Ri;
    }
  }
}

// Inverse DIT: bit-reversed in -> natural out (unnormalized).
__device__ __forceinline__ void wave_fft512_inv(v2f Xr[4], v2f Xi[4], int lane,
                                                const Tw& t) {
  { // s=1
    const float sg = (lane & 1) ? -1.0f : 1.0f;
    const v2f sgv = v2(sg, sg);
    #pragma unroll
    for (int j = 0; j < 4; ++j) {
      v2f Rr = v2(xs1(Xr[j].x), xs1(Xr[j].y));
      v2f Ri = v2(xs1(Xi[j].x), xs1(Xi[j].y));
      Xr[j] = sgv*Xr[j] + Rr; Xi[j] = sgv*Xi[j] + Ri;
    }
  }
  INV_PK_XS(2,  xs2,  t.c[7], t.s[7])
  INV_PK_XS(4,  xs4,  t.c[6], t.s[6])
  INV_PK_XS(8,  xs8,  t.c[5], t.s[5])
  INV_PK_SW(16, swp16, t.c[4], t.s[4])
  INV_PK_SW(32, swp32, t.c[3], t.s[3])
  { // s=64: intra-pair, scalar
    float wr = t.c[2], wi = t.s[2];
    #pragma unroll
    for (int j = 0; j < 4; ++j) {
      float tr = Xr[j].y*wr - Xi[j].y*wi, ti = Xr[j].y*wi + Xi[j].y*wr;
      Xr[j] = v2(Xr[j].x + tr, Xr[j].x - tr);
      Xi[j] = v2(Xi[j].x + ti, Xi[j].x - ti);
    }
  }
  { // s=128: T = {w0, w1}, w0=(c1,s1), w1=(-s1,c1)
    v2f Tr = v2(t.c[1], -t.s[1]), Ti = v2(t.s[1], t.c[1]);
    #pragma unroll
    for (int j = 0; j < 4; j += 2) {
      v2f tr = Xr[j+1]*Tr - Xi[j+1]*Ti;
      v2f ti = Xr[j+1]*Ti + Xi[j+1]*Tr;
      Xr[j+1] = Xr[j] - tr; Xi[j+1] = Xi[j] - ti;
      Xr[j]   = Xr[j] + tr; Xi[j]   = Xi[j] + ti;
    }
  }
  { // s=256: Tr1=-Ti0, Ti1=Tr0
    const float c8 = 0.70710678118654752f;
    float wr = t.c[0], wi = t.s[0];
    float w1r = c8*(wr - wi), w1i = c8*(wr + wi);
    v2f Tr0 = v2(wr, w1r), Ti0 = v2(wi, w1i);
    { v2f tr = Xr[2]*Tr0 - Xi[2]*Ti0;
      v2f ti = Xr[2]*Ti0 + Xi[2]*Tr0;
      Xr[2] = Xr[0] - tr; Xi[2] = Xi[0] - ti;
      Xr[0] = Xr[0] + tr; Xi[0] = Xi[0] + ti; }
    { v2f tr = Xr[3]*Tr0 + Xi[3]*Ti0;      // t = X3 * (-Ti0 + i*Tr0)
      v2f ti = Xr[3]*Tr0 - Xi[3]*Ti0;
      // careful: tr_true = -Xr3*Ti0 - Xi3*Tr0 ; ti_true = Xr3*Tr0 - Xi3*Ti0
      tr = -(Xr[3]*Ti0) - Xi[3]*Tr0;
      ti = Xr[3]*Tr0 - Xi[3]*Ti0;
      Xr[3] = Xr[1] - tr; Xi[3] = Xi[1] - ti;
      Xr[1] = Xr[1] + tr; Xi[1] = Xi[1] + ti; }
  }
}

// ---------------- kernels ----------------
__global__ void k_scatter(const int* __restrict__ idxx, const int* __restrict__ idxy,
                          const int* __restrict__ cid, int* __restrict__ W) {
  int p = blockIdx.x * 256 + threadIdx.x;
  int u = (idxx[p] + 256) & 511;
  int v = (idxy[p] + 256) & 511;
  atomicMax(&W[u * 512 + v], (p << 6) | cid[p]);
}

__global__ void k_pack(const int* __restrict__ W, int* __restrict__ pk) {
  int idx = blockIdx.x * 256 + threadIdx.x;
  if (idx >= 264 * 512) return;
  int j = idx >> 9, n = idx & 511;
  int out = (127 << 7) | 127;
  if (j < 257) {
    int v = (j == 256) ? 256 : brev9(2 * j);
    int u = brev9(n);
    int c1 = W[u * 512 + v];
    int c2 = W[((512 - u) & 511) * 512 + ((512 - v) & 511)];
    int a = (c1 < 0) ? 127 : (c1 & 63);
    int b = (c2 < 0) ? 127 : (c2 & 63);
    out = (b << 7) | a;
  }
  pk[j * 512 + n] = out;
}

// Two real rows per complex FFT; output TRANSPOSED: Yt[b][j][r].
__global__ __launch_bounds__(512) void k_fwd_rows(const float* __restrict__ x,
                                                  float2* __restrict__ Yt) {
  __shared__ float sm[2 * 264 * TP];
  float* tR = sm;
  float* tI = sm + 264 * TP;
  int tid = threadIdx.x, w = tid >> 6, lane = tid & 63;
  int R0 = blockIdx.x * 16;
  int bb = R0 >> 9, r0 = R0 & 511;
  const float* rowA = x + (size_t)(R0 + 2 * w) * 512;
  const float* rowB = rowA + 512;
  Tw t = make_tw(lane);
  v2f Xr[4], Xi[4];
  #pragma unroll
  for (int j = 0; j < 4; ++j) {
    Xr[j] = v2(rowA[(2*j)*64 + lane], rowA[(2*j+1)*64 + lane]);
    Xi[j] = v2(rowB[(2*j)*64 + lane], rowB[(2*j+1)*64 + lane]);
  }
  wave_fft512_fwd(Xr, Xi, lane, t);
  float* zr = sm + w * 1024;                     // wave-private scratch (in-order DS)
  float* zi = zr + 512;
  #pragma unroll
  for (int j = 0; j < 4; ++j) {
    zr[(2*j)*64 + lane] = Xr[j].x; zr[(2*j+1)*64 + lane] = Xr[j].y;
    zi[(2*j)*64 + lane] = Xi[j].x; zi[(2*j+1)*64 + lane] = Xi[j].y;
  }
  float ar[4], ai[4], br[4], bi[4];
  #pragma unroll
  for (int k = 0; k < 4; ++k) {                  // split A/B half-spectra
    int j = k * 64 + lane;
    int n2 = 2 * j;
    int kf = brev9(n2);
    int m = brev9((512 - kf) & 511);
    float er = zr[n2], ei = zi[n2];
    float mr = zr[m],  mi = zi[m];
    ar[k] = 0.5f * (er + mr); ai[k] = 0.5f * (ei - mi);
    br[k] = 0.5f * (ei + mi); bi[k] = 0.5f * (mr - er);
  }
  float a256 = zr[1], b256 = zi[1];
  __syncthreads();
  #pragma unroll
  for (int k = 0; k < 4; ++k) {
    int j = k * 64 + lane;
    tR[j*TP + 2*w]     = ar[k]; tI[j*TP + 2*w]     = ai[k];
    tR[j*TP + 2*w + 1] = br[k]; tI[j*TP + 2*w + 1] = bi[k];
  }
  if (lane == 0) {
    tR[256*TP + 2*w]     = a256; tI[256*TP + 2*w]     = 0.0f;
    tR[256*TP + 2*w + 1] = b256; tI[256*TP + 2*w + 1] = 0.0f;
  }
  __syncthreads();
  #pragma unroll
  for (int rep = 0; rep < 9; ++rep) {
    int e = rep * 512 + tid;
    int j = e >> 4, rr = e & 15;
    if (j < 257)
      Yt[((size_t)bb * 264 + j) * 512 + r0 + rr] =
        make_float2(tR[j*TP + rr], tI[j*TP + rr]);
  }
}

// Column FFT + symmetrized mask + inverse column FFT; Yt column-contiguous.
__global__ __launch_bounds__(512) void k_cols(float2* __restrict__ Yt,
                                              const int* __restrict__ pk,
                                              const float* __restrict__ pimp) {
  __shared__ float pilx[128];
  int tid = threadIdx.x;
  int b = blockIdx.x / 33, g = blockIdx.x % 33;
  if (tid < 128) pilx[tid] = (tid < 64) ? pimp[b * 64 + tid] * HALF_INV : HALF_INV;
  int w = tid >> 6, lane = tid & 63;
  int j = g * 8 + w;
  float2* col = Yt + ((size_t)b * 264 + j) * 512;
  const int* cm = pk + j * 512;
  int pcm[8];
  v2f Xr[4], Xi[4];
  #pragma unroll
  for (int q = 0; q < 4; ++q) {                  // coalesced loads + pk prefetch
    float2 v0 = col[(2*q)*64 + lane];
    float2 v1 = col[(2*q+1)*64 + lane];
    Xr[q] = v2(v0.x, v1.x); Xi[q] = v2(v0.y, v1.y);
    pcm[2*q]   = cm[(2*q)*64 + lane];
    pcm[2*q+1] = cm[(2*q+1)*64 + lane];
  }
  Tw t = make_tw(lane);
  wave_fft512_fwd(Xr, Xi, lane, t);
  __syncthreads();                               // pilx ready (hidden behind FFT)
  #pragma unroll
  for (int q = 0; q < 4; ++q) {                  // packed symmetrized mask (scale folded)
    int p0 = pcm[2*q], p1 = pcm[2*q+1];
    v2f mv = v2(pilx[p0 & 127] + pilx[(p0 >> 7) & 127],
                pilx[p1 & 127] + pilx[(p1 >> 7) & 127]);
    Xr[q] *= mv; Xi[q] *= mv;
  }
  wave_fft512_inv(Xr, Xi, lane, t);
  #pragma unroll
  for (int q = 0; q < 4; ++q) {
    col[(2*q)*64 + lane]   = make_float2(Xr[q].x, Xi[q].x);
    col[(2*q+1)*64 + lane] = make_float2(Xr[q].y, Xi[q].y);
  }
}

// Hermitian mirror + inverse row FFT -> two real rows per wave.
__global__ __launch_bounds__(512) void k_inv_rows(const float2* __restrict__ Yt,
                                                  float* __restrict__ out) {
  __shared__ float tR[264 * TP], tI[264 * TP];
  int tid = threadIdx.x, w = tid >> 6, lane = tid & 63;
  int R0 = blockIdx.x * 16;
  int bb = R0 >> 9, r0 = R0 & 511;
  #pragma unroll
  for (int rep = 0; rep < 9; ++rep) {
    int e = rep * 512 + tid;
    int j = e >> 4, rr = e & 15;
    if (j < 257) {
      float2 v = Yt[((size_t)bb * 264 + j) * 512 + r0 + rr];
      tR[j*TP + rr] = v.x; tI[j*TP + rr] = v.y;
    }
  }
  Tw t = make_tw(lane);
  __syncthreads();
  v2f Xr[4], Xi[4];
  #pragma unroll
  for (int q = 0; q < 4; ++q) {                  // C = A + i*B with Hermitian mirror
    float xr2[2], xi2[2];
    #pragma unroll
    for (int h = 0; h < 2; ++h) {
      int n = (2*q + h) * 64 + lane;
      int v9 = brev9(n);
      int j2 = brev9((512 - v9) & 511) >> 1;
      bool oddx = (n & 1) && (n != 1);
      int j = (n & 1) ? ((n == 1) ? 256 : j2) : (n >> 1);
      float s = oddx ? -1.0f : 1.0f;
      float ar = tR[j*TP + 2*w],     ai = tI[j*TP + 2*w];
      float br = tR[j*TP + 2*w + 1], bi = tI[j*TP + 2*w + 1];
      xr2[h] = ar - s * bi;
      xi2[h] = fmaf(s, ai, br);
    }
    Xr[q] = v2(xr2[0], xr2[1]); Xi[q] = v2(xi2[0], xi2[1]);
  }
  wave_fft512_inv(Xr, Xi, lane, t);
  float* orowA = out + (size_t)(R0 + 2 * w) * 512;
  float* orowB = orowA + 512;
  #pragma unroll
  for (int q = 0; q < 4; ++q) {
    orowA[(2*q)*64 + lane]   = Xr[q].x;
    orowA[(2*q+1)*64 + lane] = Xr[q].y;
    orowB[(2*q)*64 + lane]   = Xi[q].x;
    orowB[(2*q+1)*64 + lane] = Xi[q].y;
  }
}

extern "C" void kernel_launch(void* const* d_in, const int* in_sizes, int n_in,
                              void* d_out, int out_size, void* d_ws, size_t ws_size,
                              hipStream_t stream) {
  const float* x    = (const float*)d_in[0];
  const float* pimp = (const float*)d_in[1];
  const int* idxx   = (const int*)d_in[2];
  const int* idxy   = (const int*)d_in[3];
  const int* cid    = (const int*)d_in[4];

  float2* Yt = (float2*)d_ws;                                    // 69.2 MB
  int* W  = (int*)((char*)d_ws + (size_t)64 * YT_B * sizeof(float2)); // 1 MB
  int* pk = W + 512 * 512;                                       // 0.54 MB

  hipMemsetAsync(W, 0xFF, 512 * 512 * sizeof(int), stream);
  k_scatter  <<<1024, 256, 0, stream>>>(idxx, idxy, cid, W);
  k_pack     <<<(264 * 512 + 255) / 256, 256, 0, stream>>>(W, pk);
  k_fwd_rows <<<2048, 512, 0, stream>>>(x, Yt);
  k_cols     <<<64 * 33, 512, 0, stream>>>(Yt, pk, pimp);
  k_inv_rows <<<2048, 512, 0, stream>>>(Yt, (float*)d_out);
}